// Round 1
// baseline (931.763 us; speedup 1.0000x reference)
//
#include <hip/hip_runtime.h>
#include <hip/hip_bf16.h>

#define N_NODES 100000
#define N_EDGES 3200000
#define N_GRAPHS 256

// ---------------- init ----------------
__global__ __launch_bounds__(256) void init_kernel(float* dinv, int* cnt, int* cur) {
    int i = blockIdx.x * 256 + threadIdx.x;
    if (i < N_NODES) { dinv[i] = 1.0f; cnt[i] = 0; cur[i] = 0; }
}

// deg = 1 + segment_sum(ew, col); cnt = in-degree
__global__ __launch_bounds__(256) void deg_count_kernel(const int* __restrict__ col,
                                                        const float* __restrict__ ew,
                                                        float* deg, int* cnt) {
    int e = blockIdx.x * 256 + threadIdx.x;
    if (e < N_EDGES) {
        int c = col[e];
        atomicAdd(&deg[c], ew[e]);
        atomicAdd(&cnt[c], 1);
    }
}

__global__ __launch_bounds__(256) void rsqrt_kernel(float* dinv) {
    int i = blockIdx.x * 256 + threadIdx.x;
    if (i < N_NODES) dinv[i] = rsqrtf(dinv[i]);
}

// ---------------- 2-level exclusive scan of cnt -> off ----------------
// level 1: 1024 items per block (256 thr x 4)
__global__ __launch_bounds__(256) void scan1_kernel(const int* __restrict__ cnt,
                                                    int* __restrict__ off,
                                                    int* __restrict__ bsum) {
    __shared__ int s[256];
    int tid = threadIdx.x;
    int base = blockIdx.x * 1024 + tid * 4;
    int v0 = (base + 0 < N_NODES) ? cnt[base + 0] : 0;
    int v1 = (base + 1 < N_NODES) ? cnt[base + 1] : 0;
    int v2 = (base + 2 < N_NODES) ? cnt[base + 2] : 0;
    int v3 = (base + 3 < N_NODES) ? cnt[base + 3] : 0;
    int sum = v0 + v1 + v2 + v3;
    s[tid] = sum;
    __syncthreads();
    for (int d = 1; d < 256; d <<= 1) {
        int x = (tid >= d) ? s[tid - d] : 0;
        __syncthreads();
        s[tid] += x;
        __syncthreads();
    }
    int excl = s[tid] - sum;
    if (base + 0 < N_NODES) off[base + 0] = excl;
    if (base + 1 < N_NODES) off[base + 1] = excl + v0;
    if (base + 2 < N_NODES) off[base + 2] = excl + v0 + v1;
    if (base + 3 < N_NODES) off[base + 3] = excl + v0 + v1 + v2;
    if (tid == 255) bsum[blockIdx.x] = s[255];
}

// level 2: scan the 98 block sums (single block)
__global__ __launch_bounds__(256) void scan2_kernel(int* bsum, int nb) {
    __shared__ int s[256];
    int tid = threadIdx.x;
    int v = (tid < nb) ? bsum[tid] : 0;
    s[tid] = v;
    __syncthreads();
    for (int d = 1; d < 256; d <<= 1) {
        int x = (tid >= d) ? s[tid - d] : 0;
        __syncthreads();
        s[tid] += x;
        __syncthreads();
    }
    if (tid < nb) bsum[tid] = s[tid] - v;  // exclusive
}

__global__ __launch_bounds__(256) void scan3_kernel(int* off, const int* __restrict__ bsum) {
    int i = blockIdx.x * 256 + threadIdx.x;
    if (i < N_NODES) off[i] += bsum[i >> 10];
}

// ---------------- CSR scatter ----------------
// csr entry: {row, dinv[row]*ew}
__global__ __launch_bounds__(256) void scatter_kernel(const int* __restrict__ row,
                                                      const int* __restrict__ col,
                                                      const float* __restrict__ ew,
                                                      const float* __restrict__ dinv,
                                                      const int* __restrict__ off,
                                                      int* cur, int2* __restrict__ csr) {
    int e = blockIdx.x * 256 + threadIdx.x;
    if (e < N_EDGES) {
        int r = row[e], c = col[e];
        float w = dinv[r] * ew[e];
        int p = atomicAdd(&cur[c], 1);
        int2 v; v.x = r; v.y = __float_as_int(w);
        csr[off[c] + p] = v;
    }
}

// ---------------- tiled f32 GEMM: H[N,OUT] = X[N,IN] @ W[IN,OUT] ----------------
template <int IN, int OUT, int ROWS>
__global__ __launch_bounds__(256) void gemm_kernel(const float* __restrict__ X,
                                                   const float* __restrict__ W,
                                                   float* __restrict__ H, int n) {
    constexpr int BK = 16;
    constexpr int TX = OUT / 4;   // threads along cols
    constexpr int TY = ROWS / 4;  // threads along rows
    static_assert(TX * TY == 256, "block must be 256 threads");
    constexpr int XSS = ROWS + 4;
    constexpr int WSS = OUT + 4;
    __shared__ float xsT[BK][XSS];
    __shared__ float ws[BK][WSS];
    int tid = threadIdx.x;
    int tx = tid % TX, ty = tid / TX;
    int r0 = blockIdx.x * ROWS;
    float acc[4][4] = {};
    for (int k0 = 0; k0 < IN; k0 += BK) {
        // stage X tile (ROWS x 16) transposed
        constexpr int XL = (ROWS * BK) / (256 * 4);
        #pragma unroll
        for (int l = 0; l < XL; ++l) {
            int t = tid + l * 256;
            int rr = t >> 2;
            int kp = (t & 3) * 4;
            float4 v = make_float4(0.f, 0.f, 0.f, 0.f);
            int gr = r0 + rr;
            if (gr < n) v = *(const float4*)&X[(size_t)gr * IN + k0 + kp];
            xsT[kp + 0][rr] = v.x;
            xsT[kp + 1][rr] = v.y;
            xsT[kp + 2][rr] = v.z;
            xsT[kp + 3][rr] = v.w;
        }
        // stage W tile (16 x OUT)
        constexpr int WL = (BK * OUT) / 4;  // float4 count
        if (tid < WL) {
            int kr = tid / TX;
            int cp = (tid % TX) * 4;
            float4 v = *(const float4*)&W[(size_t)(k0 + kr) * OUT + cp];
            *(float4*)&ws[kr][cp] = v;
        }
        __syncthreads();
        #pragma unroll
        for (int kk = 0; kk < BK; ++kk) {
            float4 a = *(const float4*)&xsT[kk][ty * 4];
            float4 b = *(const float4*)&ws[kk][tx * 4];
            float av[4] = {a.x, a.y, a.z, a.w};
            float bv[4] = {b.x, b.y, b.z, b.w};
            #pragma unroll
            for (int i = 0; i < 4; ++i) {
                #pragma unroll
                for (int j = 0; j < 4; ++j) acc[i][j] = fmaf(av[i], bv[j], acc[i][j]);
            }
        }
        __syncthreads();
    }
    #pragma unroll
    for (int i = 0; i < 4; ++i) {
        int gr = r0 + ty * 4 + i;
        if (gr < n)
            *(float4*)&H[(size_t)gr * OUT + tx * 4] =
                make_float4(acc[i][0], acc[i][1], acc[i][2], acc[i][3]);
    }
}

// ---------------- aggregation conv1: 64 feats, wave per node ----------------
__global__ __launch_bounds__(256) void agg1_kernel(const int2* __restrict__ csr,
                                                   const int* __restrict__ off,
                                                   const int* __restrict__ cnt,
                                                   const float* __restrict__ dinv,
                                                   const float* __restrict__ h1,
                                                   const float* __restrict__ b1,
                                                   float* __restrict__ h1p) {
    int lane = threadIdx.x & 63;
    int node = blockIdx.x * 4 + (threadIdx.x >> 6);
    if (node >= N_NODES) return;
    int s = off[node], c = cnt[node];
    float acc = 0.f;
    for (int j = 0; j < c; ++j) {
        int2 e = csr[s + j];
        acc += __int_as_float(e.y) * h1[(size_t)e.x * 64 + lane];
    }
    float di = dinv[node];
    float v = acc * di + h1[(size_t)node * 64 + lane] * (di * di) + b1[lane];
    h1p[(size_t)node * 64 + lane] = fmaxf(v, 0.f);
}

// ---------------- aggregation conv2: 32 feats, wave per node, 2 edges/iter ----------------
__global__ __launch_bounds__(256) void agg2_kernel(const int2* __restrict__ csr,
                                                   const int* __restrict__ off,
                                                   const int* __restrict__ cnt,
                                                   const float* __restrict__ dinv,
                                                   const float* __restrict__ h2,
                                                   const float* __restrict__ b2,
                                                   float* __restrict__ h2p) {
    int lane = threadIdx.x & 63;
    int f = lane & 31, half = lane >> 5;
    int node = blockIdx.x * 4 + (threadIdx.x >> 6);
    if (node >= N_NODES) return;
    int s = off[node], c = cnt[node];
    float acc = 0.f;
    for (int j = half; j < c; j += 2) {
        int2 e = csr[s + j];
        acc += __int_as_float(e.y) * h2[(size_t)e.x * 32 + f];
    }
    acc += __shfl_xor(acc, 32);
    if (half == 0) {
        float di = dinv[node];
        float v = acc * di + h2[(size_t)node * 32 + f] * (di * di) + b2[f];
        h2p[(size_t)node * 32 + f] = v;
    }
}

// ---------------- pool: one block per graph (batch is sorted) ----------------
__global__ __launch_bounds__(256) void pool_kernel(const float* __restrict__ h2p,
                                                   const int* __restrict__ batch,
                                                   float* __restrict__ u) {
    int g = blockIdx.x;
    int lo = 0, hi = N_NODES;
    while (lo < hi) { int m = (lo + hi) >> 1; if (batch[m] < g) lo = m + 1; else hi = m; }
    int start = lo;
    hi = N_NODES;
    while (lo < hi) { int m = (lo + hi) >> 1; if (batch[m] < g + 1) lo = m + 1; else hi = m; }
    int end = lo;
    int f = threadIdx.x & 31, grp = threadIdx.x >> 5;
    float acc = 0.f;
    for (int n = start + grp; n < end; n += 8) acc += h2p[(size_t)n * 32 + f];
    __shared__ float red[8][32];
    red[grp][f] = acc;
    __syncthreads();
    if (threadIdx.x < 32) {
        float sum = 0.f;
        #pragma unroll
        for (int k = 0; k < 8; ++k) sum += red[k][threadIdx.x];
        u[g * 32 + threadIdx.x] = sum;
    }
}

// ---------------- MLP head: 256 graphs, one thread each ----------------
__global__ __launch_bounds__(256) void head_kernel(const float* __restrict__ u,
                                                   const float* __restrict__ Wl1,
                                                   const float* __restrict__ bl1,
                                                   const float* __restrict__ Wl2,
                                                   const float* __restrict__ bl2,
                                                   float* __restrict__ out) {
    int g = threadIdx.x;
    float uu[32];
    #pragma unroll
    for (int k = 0; k < 32; ++k) uu[k] = u[g * 32 + k];
    float o = bl2[0];
    #pragma unroll
    for (int j = 0; j < 16; ++j) {
        float h = bl1[j];
        #pragma unroll
        for (int k = 0; k < 32; ++k) h = fmaf(uu[k], Wl1[k * 16 + j], h);
        o = fmaf(fmaxf(h, 0.f), Wl2[j], o);
    }
    out[g] = o;
}

extern "C" void kernel_launch(void* const* d_in, const int* in_sizes, int n_in,
                              void* d_out, int out_size, void* d_ws, size_t ws_size,
                              hipStream_t stream) {
    const float* x     = (const float*)d_in[0];
    const int*   ei    = (const int*)d_in[1];
    const float* ew    = (const float*)d_in[2];
    const int*   batch = (const int*)d_in[3];
    const float* W1    = (const float*)d_in[4];
    const float* b1    = (const float*)d_in[5];
    const float* W2    = (const float*)d_in[6];
    const float* b2    = (const float*)d_in[7];
    const float* Wl1   = (const float*)d_in[8];
    const float* bl1   = (const float*)d_in[9];
    const float* Wl2   = (const float*)d_in[10];
    const float* bl2   = (const float*)d_in[11];
    float* out = (float*)d_out;

    const int* row = ei;
    const int* col = ei + N_EDGES;

    char* p = (char*)d_ws;
    auto alloc = [&](size_t bytes) {
        char* q = p;
        p += (bytes + 255) & ~(size_t)255;
        return q;
    };
    float* dinv   = (float*)alloc(N_NODES * 4);
    int*   cnt    = (int*)alloc(N_NODES * 4);
    int*   cur    = (int*)alloc(N_NODES * 4);
    int*   off    = (int*)alloc(N_NODES * 4);
    int*   bsum   = (int*)alloc(1024 * 4);
    int2*  csr    = (int2*)alloc((size_t)N_EDGES * 8);
    float* h1     = (float*)alloc((size_t)N_NODES * 64 * 4);
    float* h1p    = (float*)alloc((size_t)N_NODES * 64 * 4);
    float* h2     = (float*)alloc((size_t)N_NODES * 32 * 4);
    float* h2p    = (float*)alloc((size_t)N_NODES * 32 * 4);
    float* u      = (float*)alloc(N_GRAPHS * 32 * 4);

    const int gN = (N_NODES + 255) / 256;       // 391
    const int gE = (N_EDGES + 255) / 256;       // 12500
    const int nb = (N_NODES + 1023) / 1024;     // 98

    init_kernel<<<gN, 256, 0, stream>>>(dinv, cnt, cur);
    deg_count_kernel<<<gE, 256, 0, stream>>>(col, ew, dinv, cnt);
    rsqrt_kernel<<<gN, 256, 0, stream>>>(dinv);
    scan1_kernel<<<nb, 256, 0, stream>>>(cnt, off, bsum);
    scan2_kernel<<<1, 256, 0, stream>>>(bsum, nb);
    scan3_kernel<<<gN, 256, 0, stream>>>(off, bsum);
    scatter_kernel<<<gE, 256, 0, stream>>>(row, col, ew, dinv, off, cur, csr);

    gemm_kernel<128, 64, 64><<<(N_NODES + 63) / 64, 256, 0, stream>>>(x, W1, h1, N_NODES);
    agg1_kernel<<<(N_NODES + 3) / 4, 256, 0, stream>>>(csr, off, cnt, dinv, h1, b1, h1p);
    gemm_kernel<64, 32, 128><<<(N_NODES + 127) / 128, 256, 0, stream>>>(h1p, W2, h2, N_NODES);
    agg2_kernel<<<(N_NODES + 3) / 4, 256, 0, stream>>>(csr, off, cnt, dinv, h2, b2, h2p);
    pool_kernel<<<N_GRAPHS, 256, 0, stream>>>(h2p, batch, u);
    head_kernel<<<1, 256, 0, stream>>>(u, Wl1, bl1, Wl2, bl2, out);
}

// Round 2
// 664.389 us; speedup vs baseline: 1.4024x; 1.4024x over previous
//
#include <hip/hip_runtime.h>
#include <hip/hip_bf16.h>

#define N_NODES 100000
#define N_EDGES 3200000
#define N_GRAPHS 256

// ---------------- init ----------------
__global__ __launch_bounds__(256) void init_kernel(float* dinv, int* cnt, int* cur) {
    int i = blockIdx.x * 256 + threadIdx.x;
    if (i < N_NODES) { dinv[i] = 1.0f; cnt[i] = 0; cur[i] = 0; }
}

// deg = 1 + segment_sum(ew, col); cnt = in-degree
__global__ __launch_bounds__(256) void deg_count_kernel(const int* __restrict__ col,
                                                        const float* __restrict__ ew,
                                                        float* deg, int* cnt) {
    int e = blockIdx.x * 256 + threadIdx.x;
    if (e < N_EDGES) {
        int c = col[e];
        atomicAdd(&deg[c], ew[e]);
        atomicAdd(&cnt[c], 1);
    }
}

__global__ __launch_bounds__(256) void rsqrt_kernel(float* dinv) {
    int i = blockIdx.x * 256 + threadIdx.x;
    if (i < N_NODES) dinv[i] = rsqrtf(dinv[i]);
}

// ---------------- 2-level exclusive scan of cnt -> off ----------------
__global__ __launch_bounds__(256) void scan1_kernel(const int* __restrict__ cnt,
                                                    int* __restrict__ off,
                                                    int* __restrict__ bsum) {
    __shared__ int s[256];
    int tid = threadIdx.x;
    int base = blockIdx.x * 1024 + tid * 4;
    int v0 = (base + 0 < N_NODES) ? cnt[base + 0] : 0;
    int v1 = (base + 1 < N_NODES) ? cnt[base + 1] : 0;
    int v2 = (base + 2 < N_NODES) ? cnt[base + 2] : 0;
    int v3 = (base + 3 < N_NODES) ? cnt[base + 3] : 0;
    int sum = v0 + v1 + v2 + v3;
    s[tid] = sum;
    __syncthreads();
    for (int d = 1; d < 256; d <<= 1) {
        int x = (tid >= d) ? s[tid - d] : 0;
        __syncthreads();
        s[tid] += x;
        __syncthreads();
    }
    int excl = s[tid] - sum;
    if (base + 0 < N_NODES) off[base + 0] = excl;
    if (base + 1 < N_NODES) off[base + 1] = excl + v0;
    if (base + 2 < N_NODES) off[base + 2] = excl + v0 + v1;
    if (base + 3 < N_NODES) off[base + 3] = excl + v0 + v1 + v2;
    if (tid == 255) bsum[blockIdx.x] = s[255];
}

__global__ __launch_bounds__(256) void scan2_kernel(int* bsum, int nb) {
    __shared__ int s[256];
    int tid = threadIdx.x;
    int v = (tid < nb) ? bsum[tid] : 0;
    s[tid] = v;
    __syncthreads();
    for (int d = 1; d < 256; d <<= 1) {
        int x = (tid >= d) ? s[tid - d] : 0;
        __syncthreads();
        s[tid] += x;
        __syncthreads();
    }
    if (tid < nb) bsum[tid] = s[tid] - v;  // exclusive
}

__global__ __launch_bounds__(256) void scan3_kernel(int* off, const int* __restrict__ bsum) {
    int i = blockIdx.x * 256 + threadIdx.x;
    if (i < N_NODES) off[i] += bsum[i >> 10];
}

// ---------------- CSR scatter: csr entry {row, dinv[row]*ew} ----------------
__global__ __launch_bounds__(256) void scatter_kernel(const int* __restrict__ row,
                                                      const int* __restrict__ col,
                                                      const float* __restrict__ ew,
                                                      const float* __restrict__ dinv,
                                                      const int* __restrict__ off,
                                                      int* cur, int2* __restrict__ csr) {
    int e = blockIdx.x * 256 + threadIdx.x;
    if (e < N_EDGES) {
        int r = row[e], c = col[e];
        float w = dinv[r] * ew[e];
        int p = atomicAdd(&cur[c], 1);
        int2 v; v.x = r; v.y = __float_as_int(w);
        csr[off[c] + p] = v;
    }
}

// ---------------- tiled f32 GEMM: H[N,OUT] = X[N,IN] @ W[IN,OUT] ----------------
template <int IN, int OUT, int ROWS>
__global__ __launch_bounds__(256) void gemm_kernel(const float* __restrict__ X,
                                                   const float* __restrict__ W,
                                                   float* __restrict__ H, int n) {
    constexpr int BK = 16;
    constexpr int TX = OUT / 4;
    constexpr int TY = ROWS / 4;
    static_assert(TX * TY == 256, "block must be 256 threads");
    constexpr int XSS = ROWS + 4;
    constexpr int WSS = OUT + 4;
    __shared__ float xsT[BK][XSS];
    __shared__ float ws[BK][WSS];
    int tid = threadIdx.x;
    int tx = tid % TX, ty = tid / TX;
    int r0 = blockIdx.x * ROWS;
    float acc[4][4] = {};
    for (int k0 = 0; k0 < IN; k0 += BK) {
        constexpr int XL = (ROWS * BK) / (256 * 4);
        #pragma unroll
        for (int l = 0; l < XL; ++l) {
            int t = tid + l * 256;
            int rr = t >> 2;
            int kp = (t & 3) * 4;
            float4 v = make_float4(0.f, 0.f, 0.f, 0.f);
            int gr = r0 + rr;
            if (gr < n) v = *(const float4*)&X[(size_t)gr * IN + k0 + kp];
            xsT[kp + 0][rr] = v.x;
            xsT[kp + 1][rr] = v.y;
            xsT[kp + 2][rr] = v.z;
            xsT[kp + 3][rr] = v.w;
        }
        constexpr int WL = (BK * OUT) / 4;
        if (tid < WL) {
            int kr = tid / TX;
            int cp = (tid % TX) * 4;
            float4 v = *(const float4*)&W[(size_t)(k0 + kr) * OUT + cp];
            *(float4*)&ws[kr][cp] = v;
        }
        __syncthreads();
        #pragma unroll
        for (int kk = 0; kk < BK; ++kk) {
            float4 a = *(const float4*)&xsT[kk][ty * 4];
            float4 b = *(const float4*)&ws[kk][tx * 4];
            float av[4] = {a.x, a.y, a.z, a.w};
            float bv[4] = {b.x, b.y, b.z, b.w};
            #pragma unroll
            for (int i = 0; i < 4; ++i) {
                #pragma unroll
                for (int j = 0; j < 4; ++j) acc[i][j] = fmaf(av[i], bv[j], acc[i][j]);
            }
        }
        __syncthreads();
    }
    #pragma unroll
    for (int i = 0; i < 4; ++i) {
        int gr = r0 + ty * 4 + i;
        if (gr < n)
            *(float4*)&H[(size_t)gr * OUT + tx * 4] =
                make_float4(acc[i][0], acc[i][1], acc[i][2], acc[i][3]);
    }
}

// ---------------- aggregation conv1: 64 feats, wave per node ----------------
// Cooperative CSR chunk load (coalesced), readlane broadcast, 8 gathers in flight.
__global__ __launch_bounds__(256) void agg1_kernel(const int2* __restrict__ csr,
                                                   const int* __restrict__ off,
                                                   const int* __restrict__ cnt,
                                                   const float* __restrict__ dinv,
                                                   const float* __restrict__ h1,
                                                   const float* __restrict__ b1,
                                                   float* __restrict__ h1p) {
    int lane = threadIdx.x & 63;
    int node = blockIdx.x * 4 + (threadIdx.x >> 6);
    int s = off[node], c = cnt[node];
    float acc = 0.f;
    for (int j0 = 0; j0 < c; j0 += 64) {
        int m = min(64, c - j0);
        int2 e = make_int2(0, 0);
        if (lane < m) e = csr[s + j0 + lane];
        int jj = 0;
        for (; jj + 8 <= m; jj += 8) {
            int r[8], w[8];
            #pragma unroll
            for (int i = 0; i < 8; ++i) {
                r[i] = __builtin_amdgcn_readlane(e.x, jj + i);
                w[i] = __builtin_amdgcn_readlane(e.y, jj + i);
            }
            float g[8];
            #pragma unroll
            for (int i = 0; i < 8; ++i) g[i] = h1[(size_t)r[i] * 64 + lane];
            #pragma unroll
            for (int i = 0; i < 8; ++i) acc = fmaf(__int_as_float(w[i]), g[i], acc);
        }
        for (; jj < m; ++jj) {
            int r = __builtin_amdgcn_readlane(e.x, jj);
            float w = __int_as_float(__builtin_amdgcn_readlane(e.y, jj));
            acc = fmaf(w, h1[(size_t)r * 64 + lane], acc);
        }
    }
    float di = dinv[node];
    float v = acc * di + h1[(size_t)node * 64 + lane] * (di * di) + b1[lane];
    h1p[(size_t)node * 64 + lane] = fmaxf(v, 0.f);
}

// ---------------- aggregation conv2: 32 feats, 2 nodes per wave ----------------
// Each 32-lane half owns one node; per-half cooperative CSR load + shfl broadcast,
// 4 gathers in flight per half (8 per wave).
__global__ __launch_bounds__(256) void agg2_kernel(const int2* __restrict__ csr,
                                                   const int* __restrict__ off,
                                                   const int* __restrict__ cnt,
                                                   const float* __restrict__ dinv,
                                                   const float* __restrict__ h2,
                                                   const float* __restrict__ b2,
                                                   float* __restrict__ h2p) {
    int f = threadIdx.x & 31;
    int half = (threadIdx.x >> 5) & 1;
    int wid = threadIdx.x >> 6;
    int node = blockIdx.x * 8 + wid * 2 + half;
    int s = off[node], c = cnt[node];
    int base = half * 32;
    float acc = 0.f;
    for (int j0 = 0; j0 < c; j0 += 32) {
        int m = min(32, c - j0);
        int2 e = make_int2(0, 0);
        if (f < m) e = csr[s + j0 + f];
        int jj = 0;
        for (; jj + 4 <= m; jj += 4) {
            int r[4], w[4];
            #pragma unroll
            for (int i = 0; i < 4; ++i) {
                r[i] = __shfl(e.x, base + jj + i);
                w[i] = __shfl(e.y, base + jj + i);
            }
            float g[4];
            #pragma unroll
            for (int i = 0; i < 4; ++i) g[i] = h2[(size_t)r[i] * 32 + f];
            #pragma unroll
            for (int i = 0; i < 4; ++i) acc = fmaf(__int_as_float(w[i]), g[i], acc);
        }
        for (; jj < m; ++jj) {
            int r = __shfl(e.x, base + jj);
            float w = __int_as_float(__shfl(e.y, base + jj));
            acc = fmaf(w, h2[(size_t)r * 32 + f], acc);
        }
    }
    float di = dinv[node];
    float v = acc * di + h2[(size_t)node * 32 + f] * (di * di) + b2[f];
    h2p[(size_t)node * 32 + f] = v;
}

// ---------------- pool: one block per graph (batch is sorted) ----------------
__global__ __launch_bounds__(256) void pool_kernel(const float* __restrict__ h2p,
                                                   const int* __restrict__ batch,
                                                   float* __restrict__ u) {
    int g = blockIdx.x;
    int lo = 0, hi = N_NODES;
    while (lo < hi) { int m = (lo + hi) >> 1; if (batch[m] < g) lo = m + 1; else hi = m; }
    int start = lo;
    hi = N_NODES;
    while (lo < hi) { int m = (lo + hi) >> 1; if (batch[m] < g + 1) lo = m + 1; else hi = m; }
    int end = lo;
    int f = threadIdx.x & 31, grp = threadIdx.x >> 5;
    float acc = 0.f;
    for (int n = start + grp; n < end; n += 8) acc += h2p[(size_t)n * 32 + f];
    __shared__ float red[8][32];
    red[grp][f] = acc;
    __syncthreads();
    if (threadIdx.x < 32) {
        float sum = 0.f;
        #pragma unroll
        for (int k = 0; k < 8; ++k) sum += red[k][threadIdx.x];
        u[g * 32 + threadIdx.x] = sum;
    }
}

// ---------------- MLP head ----------------
__global__ __launch_bounds__(256) void head_kernel(const float* __restrict__ u,
                                                   const float* __restrict__ Wl1,
                                                   const float* __restrict__ bl1,
                                                   const float* __restrict__ Wl2,
                                                   const float* __restrict__ bl2,
                                                   float* __restrict__ out) {
    int g = threadIdx.x;
    float uu[32];
    #pragma unroll
    for (int k = 0; k < 32; ++k) uu[k] = u[g * 32 + k];
    float o = bl2[0];
    #pragma unroll
    for (int j = 0; j < 16; ++j) {
        float h = bl1[j];
        #pragma unroll
        for (int k = 0; k < 32; ++k) h = fmaf(uu[k], Wl1[k * 16 + j], h);
        o = fmaf(fmaxf(h, 0.f), Wl2[j], o);
    }
    out[g] = o;
}

extern "C" void kernel_launch(void* const* d_in, const int* in_sizes, int n_in,
                              void* d_out, int out_size, void* d_ws, size_t ws_size,
                              hipStream_t stream) {
    const float* x     = (const float*)d_in[0];
    const int*   ei    = (const int*)d_in[1];
    const float* ew    = (const float*)d_in[2];
    const int*   batch = (const int*)d_in[3];
    const float* W1    = (const float*)d_in[4];
    const float* b1    = (const float*)d_in[5];
    const float* W2    = (const float*)d_in[6];
    const float* b2    = (const float*)d_in[7];
    const float* Wl1   = (const float*)d_in[8];
    const float* bl1   = (const float*)d_in[9];
    const float* Wl2   = (const float*)d_in[10];
    const float* bl2   = (const float*)d_in[11];
    float* out = (float*)d_out;

    const int* row = ei;
    const int* col = ei + N_EDGES;

    char* p = (char*)d_ws;
    auto alloc = [&](size_t bytes) {
        char* q = p;
        p += (bytes + 255) & ~(size_t)255;
        return q;
    };
    float* dinv   = (float*)alloc(N_NODES * 4);
    int*   cnt    = (int*)alloc(N_NODES * 4);
    int*   cur    = (int*)alloc(N_NODES * 4);
    int*   off    = (int*)alloc(N_NODES * 4);
    int*   bsum   = (int*)alloc(1024 * 4);
    int2*  csr    = (int2*)alloc((size_t)N_EDGES * 8);
    float* h1     = (float*)alloc((size_t)N_NODES * 64 * 4);
    float* h1p    = (float*)alloc((size_t)N_NODES * 64 * 4);
    float* h2     = (float*)alloc((size_t)N_NODES * 32 * 4);
    float* h2p    = (float*)alloc((size_t)N_NODES * 32 * 4);
    float* u      = (float*)alloc(N_GRAPHS * 32 * 4);

    const int gN = (N_NODES + 255) / 256;
    const int gE = (N_EDGES + 255) / 256;
    const int nb = (N_NODES + 1023) / 1024;

    init_kernel<<<gN, 256, 0, stream>>>(dinv, cnt, cur);
    deg_count_kernel<<<gE, 256, 0, stream>>>(col, ew, dinv, cnt);
    rsqrt_kernel<<<gN, 256, 0, stream>>>(dinv);
    scan1_kernel<<<nb, 256, 0, stream>>>(cnt, off, bsum);
    scan2_kernel<<<1, 256, 0, stream>>>(bsum, nb);
    scan3_kernel<<<gN, 256, 0, stream>>>(off, bsum);
    scatter_kernel<<<gE, 256, 0, stream>>>(row, col, ew, dinv, off, cur, csr);

    gemm_kernel<128, 64, 64><<<(N_NODES + 63) / 64, 256, 0, stream>>>(x, W1, h1, N_NODES);
    agg1_kernel<<<(N_NODES + 3) / 4, 256, 0, stream>>>(csr, off, cnt, dinv, h1, b1, h1p);
    gemm_kernel<64, 32, 128><<<(N_NODES + 127) / 128, 256, 0, stream>>>(h1p, W2, h2, N_NODES);
    agg2_kernel<<<(N_NODES + 7) / 8, 256, 0, stream>>>(csr, off, cnt, dinv, h2, b2, h2p);
    pool_kernel<<<N_GRAPHS, 256, 0, stream>>>(h2p, batch, u);
    head_kernel<<<1, 256, 0, stream>>>(u, Wl1, bl1, Wl2, bl2, out);
}

// Round 3
// 378.508 us; speedup vs baseline: 2.4617x; 1.7553x over previous
//
#include <hip/hip_runtime.h>
#include <hip/hip_bf16.h>

#define N_NODES 100000
#define N_EDGES 3200000
#define N_GRAPHS 256

#define NBUCK 391                 // ceil(N_NODES / 256) coarse buckets (col >> 8)
#define SORT_ITEMS 4096           // edges per block in hist/scatter passes
#define NB_SORT ((N_EDGES + SORT_ITEMS - 1) / SORT_ITEMS)   // 782
#define HIST_N (NBUCK * NB_SORT)  // 305,762

// ---------------- pass 1: per-block histogram of coarse bucket ----------------
__global__ __launch_bounds__(256) void hist_kernel(const int* __restrict__ col,
                                                   int* __restrict__ hist) {
    __shared__ int h[NBUCK];
    int tid = threadIdx.x;
    for (int i = tid; i < NBUCK; i += 256) h[i] = 0;
    __syncthreads();
    int base = blockIdx.x * SORT_ITEMS;
    #pragma unroll
    for (int l = 0; l < SORT_ITEMS / 256; ++l) {
        int e = base + l * 256 + tid;
        if (e < N_EDGES) atomicAdd(&h[col[e] >> 8], 1);
    }
    __syncthreads();
    for (int i = tid; i < NBUCK; i += 256) hist[i * NB_SORT + blockIdx.x] = h[i];
}

// ---------------- scan of hist (in place): 4096/block, 2-level ----------------
__global__ __launch_bounds__(256) void scanA_kernel(int* __restrict__ a,
                                                    int* __restrict__ bsum, int n) {
    __shared__ int s[256];
    int tid = threadIdx.x;
    int base = blockIdx.x * 4096 + tid * 16;
    int v[16];
    int sum = 0;
    #pragma unroll
    for (int i = 0; i < 16; ++i) { v[i] = (base + i < n) ? a[base + i] : 0; sum += v[i]; }
    s[tid] = sum;
    __syncthreads();
    for (int d = 1; d < 256; d <<= 1) {
        int x = (tid >= d) ? s[tid - d] : 0;
        __syncthreads();
        s[tid] += x;
        __syncthreads();
    }
    int run = s[tid] - sum;
    #pragma unroll
    for (int i = 0; i < 16; ++i) {
        if (base + i < n) a[base + i] = run;
        run += v[i];
    }
    if (tid == 255) bsum[blockIdx.x] = s[255];
}

__global__ __launch_bounds__(256) void scanB_kernel(int* bsum, int nb) {
    __shared__ int s[256];
    int tid = threadIdx.x;
    int v = (tid < nb) ? bsum[tid] : 0;
    s[tid] = v;
    __syncthreads();
    for (int d = 1; d < 256; d <<= 1) {
        int x = (tid >= d) ? s[tid - d] : 0;
        __syncthreads();
        s[tid] += x;
        __syncthreads();
    }
    if (tid < nb) bsum[tid] = s[tid] - v;  // exclusive
}

__global__ __launch_bounds__(256) void scanC_kernel(int* a, const int* __restrict__ bsum, int n) {
    int i = blockIdx.x * 256 + threadIdx.x;
    if (i < n) a[i] += bsum[i >> 12];
}

// ---------------- pass 2: scatter edges into coarse-bucket regions ----------------
__global__ __launch_bounds__(256) void scatter_sort_kernel(const int* __restrict__ col,
                                                           const int* __restrict__ row,
                                                           const float* __restrict__ ew,
                                                           const int* __restrict__ hist,
                                                           int2* __restrict__ rw2,
                                                           unsigned char* __restrict__ colLoc) {
    __shared__ int offs[NBUCK];
    int tid = threadIdx.x;
    for (int i = tid; i < NBUCK; i += 256) offs[i] = hist[i * NB_SORT + blockIdx.x];
    __syncthreads();
    int base = blockIdx.x * SORT_ITEMS;
    #pragma unroll
    for (int l = 0; l < SORT_ITEMS / 256; ++l) {
        int e = base + l * 256 + tid;
        if (e < N_EDGES) {
            int c = col[e];
            int p = atomicAdd(&offs[c >> 8], 1);
            int2 v; v.x = row[e]; v.y = __float_as_int(ew[e]);
            rw2[p] = v;
            colLoc[p] = (unsigned char)(c & 255);
        }
    }
}

// ---------------- pass 3: per-bucket CSR build + deg/dinv (no global atomics) ----------------
__global__ __launch_bounds__(256) void build_kernel(const int* __restrict__ hist,
                                                    const int2* __restrict__ rw2,
                                                    const unsigned char* __restrict__ colLoc,
                                                    int* __restrict__ off,
                                                    int* __restrict__ cnt,
                                                    float* __restrict__ dinv,
                                                    int2* __restrict__ csr) {
    int b = blockIdx.x;
    int tid = threadIdx.x;
    int begin = hist[b * NB_SORT];
    int end = (b + 1 < NBUCK) ? hist[(b + 1) * NB_SORT] : N_EDGES;
    __shared__ int lcnt[256];
    __shared__ float ldeg[256];
    __shared__ int s[256];
    __shared__ int curo[256];
    lcnt[tid] = 0;
    ldeg[tid] = 0.f;
    __syncthreads();
    for (int e = begin + tid; e < end; e += 256) {
        int loc = colLoc[e];
        atomicAdd(&lcnt[loc], 1);
        atomicAdd(&ldeg[loc], __int_as_float(rw2[e].y));
    }
    __syncthreads();
    int v = lcnt[tid];
    s[tid] = v;
    __syncthreads();
    for (int d = 1; d < 256; d <<= 1) {
        int x = (tid >= d) ? s[tid - d] : 0;
        __syncthreads();
        s[tid] += x;
        __syncthreads();
    }
    int excl = s[tid] - v;
    int node = (b << 8) + tid;
    if (node < N_NODES) {
        off[node] = begin + excl;
        cnt[node] = v;
        dinv[node] = rsqrtf(1.0f + ldeg[tid]);
    }
    curo[tid] = begin + excl;
    __syncthreads();
    for (int e = begin + tid; e < end; e += 256) {
        int2 t = rw2[e];
        int loc = colLoc[e];
        int p = atomicAdd(&curo[loc], 1);
        csr[p] = t;
    }
}

// ---------------- tiled f32 GEMM: H[r,:] = (X@W)[r,:] * scale[r] ----------------
template <int IN, int OUT, int ROWS>
__global__ __launch_bounds__(256) void gemm_kernel(const float* __restrict__ X,
                                                   const float* __restrict__ W,
                                                   const float* __restrict__ scale,
                                                   float* __restrict__ H, int n) {
    constexpr int BK = 16;
    constexpr int TX = OUT / 4;
    constexpr int TY = ROWS / 4;
    static_assert(TX * TY == 256, "block must be 256 threads");
    constexpr int XSS = ROWS + 4;
    constexpr int WSS = OUT + 4;
    __shared__ float xsT[BK][XSS];
    __shared__ float ws[BK][WSS];
    int tid = threadIdx.x;
    int tx = tid % TX, ty = tid / TX;
    int r0 = blockIdx.x * ROWS;
    float acc[4][4] = {};
    for (int k0 = 0; k0 < IN; k0 += BK) {
        constexpr int XL = (ROWS * BK) / (256 * 4);
        #pragma unroll
        for (int l = 0; l < XL; ++l) {
            int t = tid + l * 256;
            int rr = t >> 2;
            int kp = (t & 3) * 4;
            float4 v = make_float4(0.f, 0.f, 0.f, 0.f);
            int gr = r0 + rr;
            if (gr < n) v = *(const float4*)&X[(size_t)gr * IN + k0 + kp];
            xsT[kp + 0][rr] = v.x;
            xsT[kp + 1][rr] = v.y;
            xsT[kp + 2][rr] = v.z;
            xsT[kp + 3][rr] = v.w;
        }
        constexpr int WL = (BK * OUT) / 4;
        if (tid < WL) {
            int kr = tid / TX;
            int cp = (tid % TX) * 4;
            float4 v = *(const float4*)&W[(size_t)(k0 + kr) * OUT + cp];
            *(float4*)&ws[kr][cp] = v;
        }
        __syncthreads();
        #pragma unroll
        for (int kk = 0; kk < BK; ++kk) {
            float4 a = *(const float4*)&xsT[kk][ty * 4];
            float4 b = *(const float4*)&ws[kk][tx * 4];
            float av[4] = {a.x, a.y, a.z, a.w};
            float bv[4] = {b.x, b.y, b.z, b.w};
            #pragma unroll
            for (int i = 0; i < 4; ++i) {
                #pragma unroll
                for (int j = 0; j < 4; ++j) acc[i][j] = fmaf(av[i], bv[j], acc[i][j]);
            }
        }
        __syncthreads();
    }
    #pragma unroll
    for (int i = 0; i < 4; ++i) {
        int gr = r0 + ty * 4 + i;
        if (gr < n) {
            float sc = scale[gr];
            *(float4*)&H[(size_t)gr * OUT + tx * 4] =
                make_float4(acc[i][0] * sc, acc[i][1] * sc, acc[i][2] * sc, acc[i][3] * sc);
        }
    }
}

// ---------------- aggregation conv1: 64 feats, wave per node ----------------
// agg = dinv[n]*(sum_e ew*h~[row] + h~[n]) + b ;  h~ = (X@W)*dinv
__global__ __launch_bounds__(256) void agg1_kernel(const int2* __restrict__ csr,
                                                   const int* __restrict__ off,
                                                   const int* __restrict__ cnt,
                                                   const float* __restrict__ dinv,
                                                   const float* __restrict__ h1t,
                                                   const float* __restrict__ b1,
                                                   float* __restrict__ h1p) {
    int lane = threadIdx.x & 63;
    int node = blockIdx.x * 4 + (threadIdx.x >> 6);
    int s = off[node], c = cnt[node];
    float acc = 0.f;
    for (int j0 = 0; j0 < c; j0 += 64) {
        int m = min(64, c - j0);
        int2 e = make_int2(0, 0);
        if (lane < m) e = csr[s + j0 + lane];
        int jj = 0;
        for (; jj + 8 <= m; jj += 8) {
            int r[8], w[8];
            #pragma unroll
            for (int i = 0; i < 8; ++i) {
                r[i] = __builtin_amdgcn_readlane(e.x, jj + i);
                w[i] = __builtin_amdgcn_readlane(e.y, jj + i);
            }
            float g[8];
            #pragma unroll
            for (int i = 0; i < 8; ++i) g[i] = h1t[(size_t)r[i] * 64 + lane];
            #pragma unroll
            for (int i = 0; i < 8; ++i) acc = fmaf(__int_as_float(w[i]), g[i], acc);
        }
        for (; jj < m; ++jj) {
            int r = __builtin_amdgcn_readlane(e.x, jj);
            float w = __int_as_float(__builtin_amdgcn_readlane(e.y, jj));
            acc = fmaf(w, h1t[(size_t)r * 64 + lane], acc);
        }
    }
    float di = dinv[node];
    float v = (acc + h1t[(size_t)node * 64 + lane]) * di + b1[lane];
    h1p[(size_t)node * 64 + lane] = fmaxf(v, 0.f);
}

// ---------------- aggregation conv2: 32 feats, 2 nodes per wave ----------------
__global__ __launch_bounds__(256) void agg2_kernel(const int2* __restrict__ csr,
                                                   const int* __restrict__ off,
                                                   const int* __restrict__ cnt,
                                                   const float* __restrict__ dinv,
                                                   const float* __restrict__ h2t,
                                                   const float* __restrict__ b2,
                                                   float* __restrict__ h2p) {
    int f = threadIdx.x & 31;
    int half = (threadIdx.x >> 5) & 1;
    int wid = threadIdx.x >> 6;
    int node = blockIdx.x * 8 + wid * 2 + half;
    int s = off[node], c = cnt[node];
    int base = half * 32;
    float acc = 0.f;
    for (int j0 = 0; j0 < c; j0 += 32) {
        int m = min(32, c - j0);
        int2 e = make_int2(0, 0);
        if (f < m) e = csr[s + j0 + f];
        int jj = 0;
        for (; jj + 4 <= m; jj += 4) {
            int r[4], w[4];
            #pragma unroll
            for (int i = 0; i < 4; ++i) {
                r[i] = __shfl(e.x, base + jj + i);
                w[i] = __shfl(e.y, base + jj + i);
            }
            float g[4];
            #pragma unroll
            for (int i = 0; i < 4; ++i) g[i] = h2t[(size_t)r[i] * 32 + f];
            #pragma unroll
            for (int i = 0; i < 4; ++i) acc = fmaf(__int_as_float(w[i]), g[i], acc);
        }
        for (; jj < m; ++jj) {
            int r = __shfl(e.x, base + jj);
            float w = __int_as_float(__shfl(e.y, base + jj));
            acc = fmaf(w, h2t[(size_t)r * 32 + f], acc);
        }
    }
    float di = dinv[node];
    float v = (acc + h2t[(size_t)node * 32 + f]) * di + b2[f];
    h2p[(size_t)node * 32 + f] = v;
}

// ---------------- pool: one block per graph (batch is sorted) ----------------
__global__ __launch_bounds__(256) void pool_kernel(const float* __restrict__ h2p,
                                                   const int* __restrict__ batch,
                                                   float* __restrict__ u) {
    int g = blockIdx.x;
    int lo = 0, hi = N_NODES;
    while (lo < hi) { int m = (lo + hi) >> 1; if (batch[m] < g) lo = m + 1; else hi = m; }
    int start = lo;
    hi = N_NODES;
    while (lo < hi) { int m = (lo + hi) >> 1; if (batch[m] < g + 1) lo = m + 1; else hi = m; }
    int end = lo;
    int f = threadIdx.x & 31, grp = threadIdx.x >> 5;
    float acc = 0.f;
    for (int n = start + grp; n < end; n += 8) acc += h2p[(size_t)n * 32 + f];
    __shared__ float red[8][32];
    red[grp][f] = acc;
    __syncthreads();
    if (threadIdx.x < 32) {
        float sum = 0.f;
        #pragma unroll
        for (int k = 0; k < 8; ++k) sum += red[k][threadIdx.x];
        u[g * 32 + threadIdx.x] = sum;
    }
}

// ---------------- MLP head ----------------
__global__ __launch_bounds__(256) void head_kernel(const float* __restrict__ u,
                                                   const float* __restrict__ Wl1,
                                                   const float* __restrict__ bl1,
                                                   const float* __restrict__ Wl2,
                                                   const float* __restrict__ bl2,
                                                   float* __restrict__ out) {
    int g = threadIdx.x;
    float uu[32];
    #pragma unroll
    for (int k = 0; k < 32; ++k) uu[k] = u[g * 32 + k];
    float o = bl2[0];
    #pragma unroll
    for (int j = 0; j < 16; ++j) {
        float h = bl1[j];
        #pragma unroll
        for (int k = 0; k < 32; ++k) h = fmaf(uu[k], Wl1[k * 16 + j], h);
        o = fmaf(fmaxf(h, 0.f), Wl2[j], o);
    }
    out[g] = o;
}

extern "C" void kernel_launch(void* const* d_in, const int* in_sizes, int n_in,
                              void* d_out, int out_size, void* d_ws, size_t ws_size,
                              hipStream_t stream) {
    const float* x     = (const float*)d_in[0];
    const int*   ei    = (const int*)d_in[1];
    const float* ew    = (const float*)d_in[2];
    const int*   batch = (const int*)d_in[3];
    const float* W1    = (const float*)d_in[4];
    const float* b1    = (const float*)d_in[5];
    const float* W2    = (const float*)d_in[6];
    const float* b2    = (const float*)d_in[7];
    const float* Wl1   = (const float*)d_in[8];
    const float* bl1   = (const float*)d_in[9];
    const float* Wl2   = (const float*)d_in[10];
    const float* bl2   = (const float*)d_in[11];
    float* out = (float*)d_out;

    const int* row = ei;
    const int* col = ei + N_EDGES;

    char* p = (char*)d_ws;
    auto alloc = [&](size_t bytes) {
        char* q = p;
        p += (bytes + 255) & ~(size_t)255;
        return q;
    };
    int*   hist   = (int*)alloc((size_t)HIST_N * 4);
    int*   bsum   = (int*)alloc(1024 * 4);
    int2*  rw2    = (int2*)alloc((size_t)N_EDGES * 8);
    unsigned char* colLoc = (unsigned char*)alloc(N_EDGES);
    int*   off    = (int*)alloc(N_NODES * 4);
    int*   cnt    = (int*)alloc(N_NODES * 4);
    float* dinv   = (float*)alloc(N_NODES * 4);
    int2*  csr    = (int2*)alloc((size_t)N_EDGES * 8);
    float* h1t    = (float*)rw2;  // alias: rw2 dead after build_kernel; both 25.6 MB
    float* h1p    = (float*)alloc((size_t)N_NODES * 64 * 4);
    float* h2t    = (float*)alloc((size_t)N_NODES * 32 * 4);
    float* h2p    = (float*)alloc((size_t)N_NODES * 32 * 4);
    float* u      = (float*)alloc(N_GRAPHS * 32 * 4);

    const int nbScan = (HIST_N + 4095) / 4096;  // 75

    hist_kernel<<<NB_SORT, 256, 0, stream>>>(col, hist);
    scanA_kernel<<<nbScan, 256, 0, stream>>>(hist, bsum, HIST_N);
    scanB_kernel<<<1, 256, 0, stream>>>(bsum, nbScan);
    scanC_kernel<<<(HIST_N + 255) / 256, 256, 0, stream>>>(hist, bsum, HIST_N);
    scatter_sort_kernel<<<NB_SORT, 256, 0, stream>>>(col, row, ew, hist, rw2, colLoc);
    build_kernel<<<NBUCK, 256, 0, stream>>>(hist, rw2, colLoc, off, cnt, dinv, csr);

    gemm_kernel<128, 64, 64><<<(N_NODES + 63) / 64, 256, 0, stream>>>(x, W1, dinv, h1t, N_NODES);
    agg1_kernel<<<(N_NODES + 3) / 4, 256, 0, stream>>>(csr, off, cnt, dinv, h1t, b1, h1p);
    gemm_kernel<64, 32, 128><<<(N_NODES + 127) / 128, 256, 0, stream>>>(h1p, W2, dinv, h2t, N_NODES);
    agg2_kernel<<<(N_NODES + 7) / 8, 256, 0, stream>>>(csr, off, cnt, dinv, h2t, b2, h2p);
    pool_kernel<<<N_GRAPHS, 256, 0, stream>>>(h2p, batch, u);
    head_kernel<<<1, 256, 0, stream>>>(u, Wl1, bl1, Wl2, bl2, out);
}

// Round 4
// 327.814 us; speedup vs baseline: 2.8424x; 1.1546x over previous
//
#include <hip/hip_runtime.h>
#include <hip/hip_bf16.h>

#define N_NODES 100000
#define N_EDGES 3200000
#define N_GRAPHS 256

#define NBUCK 391                 // ceil(N_NODES / 256) coarse buckets (col >> 8)
#define SORT_ITEMS 2048           // edges per block in hist/scatter passes
#define NB_SORT ((N_EDGES + SORT_ITEMS - 1) / SORT_ITEMS)   // 1563
#define HIST_N (NBUCK * NB_SORT)  // 611,133
#define ROW_MASK 131071           // 2^17 - 1 (N_NODES < 2^17)

// ---------------- pass 1: per-block histogram of coarse bucket ----------------
__global__ __launch_bounds__(256) void hist_kernel(const int* __restrict__ col,
                                                   int* __restrict__ hist) {
    __shared__ int h[NBUCK];
    int tid = threadIdx.x;
    for (int i = tid; i < NBUCK; i += 256) h[i] = 0;
    __syncthreads();
    int base = blockIdx.x * SORT_ITEMS + tid * 4;
    #pragma unroll
    for (int l = 0; l < SORT_ITEMS / 1024; ++l) {
        int e = base + l * 1024;
        if (e < N_EDGES) {  // N_EDGES % 4 == 0, e % 4 == 0 -> whole int4 in range
            int4 c4 = *(const int4*)&col[e];
            atomicAdd(&h[c4.x >> 8], 1);
            atomicAdd(&h[c4.y >> 8], 1);
            atomicAdd(&h[c4.z >> 8], 1);
            atomicAdd(&h[c4.w >> 8], 1);
        }
    }
    __syncthreads();
    for (int i = tid; i < NBUCK; i += 256) hist[i * NB_SORT + blockIdx.x] = h[i];
}

// ---------------- scan of hist (in place): 4096/block, 2-level ----------------
__global__ __launch_bounds__(256) void scanA_kernel(int* __restrict__ a,
                                                    int* __restrict__ bsum, int n) {
    __shared__ int s[256];
    int tid = threadIdx.x;
    int base = blockIdx.x * 4096 + tid * 16;
    int v[16];
    int sum = 0;
    #pragma unroll
    for (int i = 0; i < 16; ++i) { v[i] = (base + i < n) ? a[base + i] : 0; sum += v[i]; }
    s[tid] = sum;
    __syncthreads();
    for (int d = 1; d < 256; d <<= 1) {
        int x = (tid >= d) ? s[tid - d] : 0;
        __syncthreads();
        s[tid] += x;
        __syncthreads();
    }
    int run = s[tid] - sum;
    #pragma unroll
    for (int i = 0; i < 16; ++i) {
        if (base + i < n) a[base + i] = run;
        run += v[i];
    }
    if (tid == 255) bsum[blockIdx.x] = s[255];
}

__global__ __launch_bounds__(256) void scanB_kernel(int* bsum, int nb) {
    __shared__ int s[256];
    int tid = threadIdx.x;
    int v = (tid < nb) ? bsum[tid] : 0;
    s[tid] = v;
    __syncthreads();
    for (int d = 1; d < 256; d <<= 1) {
        int x = (tid >= d) ? s[tid - d] : 0;
        __syncthreads();
        s[tid] += x;
        __syncthreads();
    }
    if (tid < nb) bsum[tid] = s[tid] - v;  // exclusive
}

__global__ __launch_bounds__(256) void scanC_kernel(int* a, const int* __restrict__ bsum, int n) {
    int i = blockIdx.x * 256 + threadIdx.x;
    if (i < n) a[i] += bsum[i >> 12];
}

// ---------------- pass 2: scatter edges into coarse-bucket regions ----------------
// rw2 entry: { row | (col&255)<<17 , ew } — loc packed, no separate byte stream.
__global__ __launch_bounds__(256) void scatter_sort_kernel(const int* __restrict__ col,
                                                           const int* __restrict__ row,
                                                           const float* __restrict__ ew,
                                                           const int* __restrict__ hist,
                                                           int2* __restrict__ rw2) {
    __shared__ int offs[NBUCK];
    int tid = threadIdx.x;
    for (int i = tid; i < NBUCK; i += 256) offs[i] = hist[i * NB_SORT + blockIdx.x];
    __syncthreads();
    int base = blockIdx.x * SORT_ITEMS + tid * 4;
    #pragma unroll
    for (int l = 0; l < SORT_ITEMS / 1024; ++l) {
        int e = base + l * 1024;
        if (e < N_EDGES) {
            int4 c4 = *(const int4*)&col[e];
            int4 r4 = *(const int4*)&row[e];
            float4 w4 = *(const float4*)&ew[e];
            int p0 = atomicAdd(&offs[c4.x >> 8], 1);
            int p1 = atomicAdd(&offs[c4.y >> 8], 1);
            int p2 = atomicAdd(&offs[c4.z >> 8], 1);
            int p3 = atomicAdd(&offs[c4.w >> 8], 1);
            int2 v0; v0.x = r4.x | ((c4.x & 255) << 17); v0.y = __float_as_int(w4.x);
            int2 v1; v1.x = r4.y | ((c4.y & 255) << 17); v1.y = __float_as_int(w4.y);
            int2 v2; v2.x = r4.z | ((c4.z & 255) << 17); v2.y = __float_as_int(w4.z);
            int2 v3; v3.x = r4.w | ((c4.w & 255) << 17); v3.y = __float_as_int(w4.w);
            rw2[p0] = v0;
            rw2[p1] = v1;
            rw2[p2] = v2;
            rw2[p3] = v3;
        }
    }
}

// ---------------- pass 3: per-bucket CSR build + deg/dinv (no global atomics) ----------------
__global__ __launch_bounds__(256) void build_kernel(const int* __restrict__ hist,
                                                    const int2* __restrict__ rw2,
                                                    int* __restrict__ off,
                                                    int* __restrict__ cnt,
                                                    float* __restrict__ dinv,
                                                    int2* __restrict__ csr) {
    int b = blockIdx.x;
    int tid = threadIdx.x;
    int begin = hist[b * NB_SORT];
    int end = (b + 1 < NBUCK) ? hist[(b + 1) * NB_SORT] : N_EDGES;
    __shared__ int lcnt[256];
    __shared__ float ldeg[256];
    __shared__ int s[256];
    __shared__ int curo[256];
    lcnt[tid] = 0;
    ldeg[tid] = 0.f;
    __syncthreads();
    for (int e = begin + tid; e < end; e += 512) {
        int2 a = rw2[e];
        int e2 = e + 256;
        int2 c = (e2 < end) ? rw2[e2] : make_int2(0, 0);
        atomicAdd(&lcnt[a.x >> 17], 1);
        atomicAdd(&ldeg[a.x >> 17], __int_as_float(a.y));
        if (e2 < end) {
            atomicAdd(&lcnt[c.x >> 17], 1);
            atomicAdd(&ldeg[c.x >> 17], __int_as_float(c.y));
        }
    }
    __syncthreads();
    int v = lcnt[tid];
    s[tid] = v;
    __syncthreads();
    for (int d = 1; d < 256; d <<= 1) {
        int x = (tid >= d) ? s[tid - d] : 0;
        __syncthreads();
        s[tid] += x;
        __syncthreads();
    }
    int excl = s[tid] - v;
    int node = (b << 8) + tid;
    if (node < N_NODES) {
        off[node] = begin + excl;
        cnt[node] = v;
        dinv[node] = rsqrtf(1.0f + ldeg[tid]);
    }
    curo[tid] = begin + excl;
    __syncthreads();
    for (int e = begin + tid; e < end; e += 512) {
        int2 a = rw2[e];
        int e2 = e + 256;
        int2 c = (e2 < end) ? rw2[e2] : make_int2(0, 0);
        int pa = atomicAdd(&curo[a.x >> 17], 1);
        csr[pa] = make_int2(a.x & ROW_MASK, a.y);
        if (e2 < end) {
            int pc = atomicAdd(&curo[c.x >> 17], 1);
            csr[pc] = make_int2(c.x & ROW_MASK, c.y);
        }
    }
}

// ---------------- tiled f32 GEMM: H[r,:] = (X@W)[r,:] * scale[r] ----------------
template <int IN, int OUT, int ROWS>
__global__ __launch_bounds__(256) void gemm_kernel(const float* __restrict__ X,
                                                   const float* __restrict__ W,
                                                   const float* __restrict__ scale,
                                                   float* __restrict__ H, int n) {
    constexpr int BK = 16;
    constexpr int TX = OUT / 4;
    constexpr int TY = ROWS / 4;
    static_assert(TX * TY == 256, "block must be 256 threads");
    constexpr int XSS = ROWS + 4;
    constexpr int WSS = OUT + 4;
    __shared__ float xsT[BK][XSS];
    __shared__ float ws[BK][WSS];
    int tid = threadIdx.x;
    int tx = tid % TX, ty = tid / TX;
    int r0 = blockIdx.x * ROWS;
    float acc[4][4] = {};
    for (int k0 = 0; k0 < IN; k0 += BK) {
        constexpr int XL = (ROWS * BK) / (256 * 4);
        #pragma unroll
        for (int l = 0; l < XL; ++l) {
            int t = tid + l * 256;
            int rr = t >> 2;
            int kp = (t & 3) * 4;
            float4 v = make_float4(0.f, 0.f, 0.f, 0.f);
            int gr = r0 + rr;
            if (gr < n) v = *(const float4*)&X[(size_t)gr * IN + k0 + kp];
            xsT[kp + 0][rr] = v.x;
            xsT[kp + 1][rr] = v.y;
            xsT[kp + 2][rr] = v.z;
            xsT[kp + 3][rr] = v.w;
        }
        constexpr int WL = (BK * OUT) / 4;
        if (tid < WL) {
            int kr = tid / TX;
            int cp = (tid % TX) * 4;
            float4 v = *(const float4*)&W[(size_t)(k0 + kr) * OUT + cp];
            *(float4*)&ws[kr][cp] = v;
        }
        __syncthreads();
        #pragma unroll
        for (int kk = 0; kk < BK; ++kk) {
            float4 a = *(const float4*)&xsT[kk][ty * 4];
            float4 b = *(const float4*)&ws[kk][tx * 4];
            float av[4] = {a.x, a.y, a.z, a.w};
            float bv[4] = {b.x, b.y, b.z, b.w};
            #pragma unroll
            for (int i = 0; i < 4; ++i) {
                #pragma unroll
                for (int j = 0; j < 4; ++j) acc[i][j] = fmaf(av[i], bv[j], acc[i][j]);
            }
        }
        __syncthreads();
    }
    #pragma unroll
    for (int i = 0; i < 4; ++i) {
        int gr = r0 + ty * 4 + i;
        if (gr < n) {
            float sc = scale[gr];
            *(float4*)&H[(size_t)gr * OUT + tx * 4] =
                make_float4(acc[i][0] * sc, acc[i][1] * sc, acc[i][2] * sc, acc[i][3] * sc);
        }
    }
}

// ---------------- aggregation conv1: 64 feats, wave per node ----------------
// agg = dinv[n]*(sum_e ew*h~[row] + h~[n]) + b ;  h~ = (X@W)*dinv
__global__ __launch_bounds__(256) void agg1_kernel(const int2* __restrict__ csr,
                                                   const int* __restrict__ off,
                                                   const int* __restrict__ cnt,
                                                   const float* __restrict__ dinv,
                                                   const float* __restrict__ h1t,
                                                   const float* __restrict__ b1,
                                                   float* __restrict__ h1p) {
    int lane = threadIdx.x & 63;
    int node = blockIdx.x * 4 + (threadIdx.x >> 6);
    int s = off[node], c = cnt[node];
    float acc = 0.f;
    for (int j0 = 0; j0 < c; j0 += 64) {
        int m = min(64, c - j0);
        int2 e = make_int2(0, 0);
        if (lane < m) e = csr[s + j0 + lane];
        int jj = 0;
        for (; jj + 8 <= m; jj += 8) {
            int r[8], w[8];
            #pragma unroll
            for (int i = 0; i < 8; ++i) {
                r[i] = __builtin_amdgcn_readlane(e.x, jj + i);
                w[i] = __builtin_amdgcn_readlane(e.y, jj + i);
            }
            float g[8];
            #pragma unroll
            for (int i = 0; i < 8; ++i) g[i] = h1t[(size_t)r[i] * 64 + lane];
            #pragma unroll
            for (int i = 0; i < 8; ++i) acc = fmaf(__int_as_float(w[i]), g[i], acc);
        }
        for (; jj < m; ++jj) {
            int r = __builtin_amdgcn_readlane(e.x, jj);
            float w = __int_as_float(__builtin_amdgcn_readlane(e.y, jj));
            acc = fmaf(w, h1t[(size_t)r * 64 + lane], acc);
        }
    }
    float di = dinv[node];
    float v = (acc + h1t[(size_t)node * 64 + lane]) * di + b1[lane];
    h1p[(size_t)node * 64 + lane] = fmaxf(v, 0.f);
}

// ---------------- aggregation conv2: 32 feats, 2 nodes per wave ----------------
__global__ __launch_bounds__(256) void agg2_kernel(const int2* __restrict__ csr,
                                                   const int* __restrict__ off,
                                                   const int* __restrict__ cnt,
                                                   const float* __restrict__ dinv,
                                                   const float* __restrict__ h2t,
                                                   const float* __restrict__ b2,
                                                   float* __restrict__ h2p) {
    int f = threadIdx.x & 31;
    int half = (threadIdx.x >> 5) & 1;
    int wid = threadIdx.x >> 6;
    int node = blockIdx.x * 8 + wid * 2 + half;
    int s = off[node], c = cnt[node];
    int base = half * 32;
    float acc = 0.f;
    for (int j0 = 0; j0 < c; j0 += 32) {
        int m = min(32, c - j0);
        int2 e = make_int2(0, 0);
        if (f < m) e = csr[s + j0 + f];
        int jj = 0;
        for (; jj + 4 <= m; jj += 4) {
            int r[4], w[4];
            #pragma unroll
            for (int i = 0; i < 4; ++i) {
                r[i] = __shfl(e.x, base + jj + i);
                w[i] = __shfl(e.y, base + jj + i);
            }
            float g[4];
            #pragma unroll
            for (int i = 0; i < 4; ++i) g[i] = h2t[(size_t)r[i] * 32 + f];
            #pragma unroll
            for (int i = 0; i < 4; ++i) acc = fmaf(__int_as_float(w[i]), g[i], acc);
        }
        for (; jj < m; ++jj) {
            int r = __shfl(e.x, base + jj);
            float w = __int_as_float(__shfl(e.y, base + jj));
            acc = fmaf(w, h2t[(size_t)r * 32 + f], acc);
        }
    }
    float di = dinv[node];
    float v = (acc + h2t[(size_t)node * 32 + f]) * di + b2[f];
    h2p[(size_t)node * 32 + f] = v;
}

// ---------------- pool: one block per graph (batch is sorted) ----------------
__global__ __launch_bounds__(256) void pool_kernel(const float* __restrict__ h2p,
                                                   const int* __restrict__ batch,
                                                   float* __restrict__ u) {
    int g = blockIdx.x;
    int lo = 0, hi = N_NODES;
    while (lo < hi) { int m = (lo + hi) >> 1; if (batch[m] < g) lo = m + 1; else hi = m; }
    int start = lo;
    hi = N_NODES;
    while (lo < hi) { int m = (lo + hi) >> 1; if (batch[m] < g + 1) lo = m + 1; else hi = m; }
    int end = lo;
    int f = threadIdx.x & 31, grp = threadIdx.x >> 5;
    float acc = 0.f;
    for (int n = start + grp; n < end; n += 8) acc += h2p[(size_t)n * 32 + f];
    __shared__ float red[8][32];
    red[grp][f] = acc;
    __syncthreads();
    if (threadIdx.x < 32) {
        float sum = 0.f;
        #pragma unroll
        for (int k = 0; k < 8; ++k) sum += red[k][threadIdx.x];
        u[g * 32 + threadIdx.x] = sum;
    }
}

// ---------------- MLP head ----------------
__global__ __launch_bounds__(256) void head_kernel(const float* __restrict__ u,
                                                   const float* __restrict__ Wl1,
                                                   const float* __restrict__ bl1,
                                                   const float* __restrict__ Wl2,
                                                   const float* __restrict__ bl2,
                                                   float* __restrict__ out) {
    int g = threadIdx.x;
    float uu[32];
    #pragma unroll
    for (int k = 0; k < 32; ++k) uu[k] = u[g * 32 + k];
    float o = bl2[0];
    #pragma unroll
    for (int j = 0; j < 16; ++j) {
        float h = bl1[j];
        #pragma unroll
        for (int k = 0; k < 32; ++k) h = fmaf(uu[k], Wl1[k * 16 + j], h);
        o = fmaf(fmaxf(h, 0.f), Wl2[j], o);
    }
    out[g] = o;
}

extern "C" void kernel_launch(void* const* d_in, const int* in_sizes, int n_in,
                              void* d_out, int out_size, void* d_ws, size_t ws_size,
                              hipStream_t stream) {
    const float* x     = (const float*)d_in[0];
    const int*   ei    = (const int*)d_in[1];
    const float* ew    = (const float*)d_in[2];
    const int*   batch = (const int*)d_in[3];
    const float* W1    = (const float*)d_in[4];
    const float* b1    = (const float*)d_in[5];
    const float* W2    = (const float*)d_in[6];
    const float* b2    = (const float*)d_in[7];
    const float* Wl1   = (const float*)d_in[8];
    const float* bl1   = (const float*)d_in[9];
    const float* Wl2   = (const float*)d_in[10];
    const float* bl2   = (const float*)d_in[11];
    float* out = (float*)d_out;

    const int* row = ei;
    const int* col = ei + N_EDGES;

    char* p = (char*)d_ws;
    auto alloc = [&](size_t bytes) {
        char* q = p;
        p += (bytes + 255) & ~(size_t)255;
        return q;
    };
    int*   hist   = (int*)alloc((size_t)HIST_N * 4);
    int*   bsum   = (int*)alloc(1024 * 4);
    int2*  rw2    = (int2*)alloc((size_t)N_EDGES * 8);
    int*   off    = (int*)alloc(N_NODES * 4);
    int*   cnt    = (int*)alloc(N_NODES * 4);
    float* dinv   = (float*)alloc(N_NODES * 4);
    int2*  csr    = (int2*)alloc((size_t)N_EDGES * 8);
    float* h1t    = (float*)rw2;  // alias: rw2 dead after build_kernel; both 25.6 MB
    float* h1p    = (float*)alloc((size_t)N_NODES * 64 * 4);
    float* h2t    = (float*)alloc((size_t)N_NODES * 32 * 4);
    float* h2p    = (float*)alloc((size_t)N_NODES * 32 * 4);
    float* u      = (float*)alloc(N_GRAPHS * 32 * 4);

    const int nbScan = (HIST_N + 4095) / 4096;  // 150

    hist_kernel<<<NB_SORT, 256, 0, stream>>>(col, hist);
    scanA_kernel<<<nbScan, 256, 0, stream>>>(hist, bsum, HIST_N);
    scanB_kernel<<<1, 256, 0, stream>>>(bsum, nbScan);
    scanC_kernel<<<(HIST_N + 255) / 256, 256, 0, stream>>>(hist, bsum, HIST_N);
    scatter_sort_kernel<<<NB_SORT, 256, 0, stream>>>(col, row, ew, hist, rw2);
    build_kernel<<<NBUCK, 256, 0, stream>>>(hist, rw2, off, cnt, dinv, csr);

    gemm_kernel<128, 64, 64><<<(N_NODES + 63) / 64, 256, 0, stream>>>(x, W1, dinv, h1t, N_NODES);
    agg1_kernel<<<(N_NODES + 3) / 4, 256, 0, stream>>>(csr, off, cnt, dinv, h1t, b1, h1p);
    gemm_kernel<64, 32, 128><<<(N_NODES + 127) / 128, 256, 0, stream>>>(h1p, W2, dinv, h2t, N_NODES);
    agg2_kernel<<<(N_NODES + 7) / 8, 256, 0, stream>>>(csr, off, cnt, dinv, h2t, b2, h2p);
    pool_kernel<<<N_GRAPHS, 256, 0, stream>>>(h2p, batch, u);
    head_kernel<<<1, 256, 0, stream>>>(u, Wl1, bl1, Wl2, bl2, out);
}

// Round 5
// 285.298 us; speedup vs baseline: 3.2659x; 1.1490x over previous
//
#include <hip/hip_runtime.h>
#include <hip/hip_bf16.h>

#define N_NODES 100000
#define N_EDGES 3200000
#define N_GRAPHS 256

#define NBUCK 391                 // ceil(N_NODES / 256) coarse buckets (col >> 8)
#define SORT_ITEMS 2048           // edges per block in hist/scatter passes
#define NB_SORT ((N_EDGES + SORT_ITEMS - 1) / SORT_ITEMS)   // 1563
#define HIST_N (NBUCK * NB_SORT)  // 611,133
#define ROW_MASK 131071           // 2^17 - 1 (N_NODES < 2^17)

__device__ __forceinline__ float bf2f(unsigned short u) {
    return __uint_as_float(((unsigned)u) << 16);
}
__device__ __forceinline__ unsigned short f2bf(float f) {
    __hip_bfloat16 b = __float2bfloat16(f);
    return *(unsigned short*)&b;
}

// ---------------- pass 1: per-block histogram of coarse bucket ----------------
__global__ __launch_bounds__(256) void hist_kernel(const int* __restrict__ col,
                                                   int* __restrict__ hist) {
    __shared__ int h[NBUCK];
    int tid = threadIdx.x;
    for (int i = tid; i < NBUCK; i += 256) h[i] = 0;
    __syncthreads();
    int base = blockIdx.x * SORT_ITEMS + tid * 4;
    #pragma unroll
    for (int l = 0; l < SORT_ITEMS / 1024; ++l) {
        int e = base + l * 1024;
        if (e < N_EDGES) {
            int4 c4 = *(const int4*)&col[e];
            atomicAdd(&h[c4.x >> 8], 1);
            atomicAdd(&h[c4.y >> 8], 1);
            atomicAdd(&h[c4.z >> 8], 1);
            atomicAdd(&h[c4.w >> 8], 1);
        }
    }
    __syncthreads();
    for (int i = tid; i < NBUCK; i += 256) hist[i * NB_SORT + blockIdx.x] = h[i];
}

// ---------------- scan of hist (in place): 4096/block, 2-level ----------------
__global__ __launch_bounds__(256) void scanA_kernel(int* __restrict__ a,
                                                    int* __restrict__ bsum, int n) {
    __shared__ int s[256];
    int tid = threadIdx.x;
    int base = blockIdx.x * 4096 + tid * 16;
    int v[16];
    int sum = 0;
    #pragma unroll
    for (int i = 0; i < 16; ++i) { v[i] = (base + i < n) ? a[base + i] : 0; sum += v[i]; }
    s[tid] = sum;
    __syncthreads();
    for (int d = 1; d < 256; d <<= 1) {
        int x = (tid >= d) ? s[tid - d] : 0;
        __syncthreads();
        s[tid] += x;
        __syncthreads();
    }
    int run = s[tid] - sum;
    #pragma unroll
    for (int i = 0; i < 16; ++i) {
        if (base + i < n) a[base + i] = run;
        run += v[i];
    }
    if (tid == 255) bsum[blockIdx.x] = s[255];
}

__global__ __launch_bounds__(256) void scanB_kernel(int* bsum, int nb) {
    __shared__ int s[256];
    int tid = threadIdx.x;
    int v = (tid < nb) ? bsum[tid] : 0;
    s[tid] = v;
    __syncthreads();
    for (int d = 1; d < 256; d <<= 1) {
        int x = (tid >= d) ? s[tid - d] : 0;
        __syncthreads();
        s[tid] += x;
        __syncthreads();
    }
    if (tid < nb) bsum[tid] = s[tid] - v;  // exclusive
}

__global__ __launch_bounds__(256) void scanC_kernel(int* a, const int* __restrict__ bsum, int n) {
    int i = blockIdx.x * 256 + threadIdx.x;
    if (i < n) a[i] += bsum[i >> 12];
}

// ---------------- pass 2: scatter edges into coarse-bucket regions ----------------
// rw2 entry: { row | (col&255)<<17 , ew }
__global__ __launch_bounds__(256) void scatter_sort_kernel(const int* __restrict__ col,
                                                           const int* __restrict__ row,
                                                           const float* __restrict__ ew,
                                                           const int* __restrict__ hist,
                                                           int2* __restrict__ rw2) {
    __shared__ int offs[NBUCK];
    int tid = threadIdx.x;
    for (int i = tid; i < NBUCK; i += 256) offs[i] = hist[i * NB_SORT + blockIdx.x];
    __syncthreads();
    int base = blockIdx.x * SORT_ITEMS + tid * 4;
    #pragma unroll
    for (int l = 0; l < SORT_ITEMS / 1024; ++l) {
        int e = base + l * 1024;
        if (e < N_EDGES) {
            int4 c4 = *(const int4*)&col[e];
            int4 r4 = *(const int4*)&row[e];
            float4 w4 = *(const float4*)&ew[e];
            int p0 = atomicAdd(&offs[c4.x >> 8], 1);
            int p1 = atomicAdd(&offs[c4.y >> 8], 1);
            int p2 = atomicAdd(&offs[c4.z >> 8], 1);
            int p3 = atomicAdd(&offs[c4.w >> 8], 1);
            int2 v0; v0.x = r4.x | ((c4.x & 255) << 17); v0.y = __float_as_int(w4.x);
            int2 v1; v1.x = r4.y | ((c4.y & 255) << 17); v1.y = __float_as_int(w4.y);
            int2 v2; v2.x = r4.z | ((c4.z & 255) << 17); v2.y = __float_as_int(w4.z);
            int2 v3; v3.x = r4.w | ((c4.w & 255) << 17); v3.y = __float_as_int(w4.w);
            rw2[p0] = v0;
            rw2[p1] = v1;
            rw2[p2] = v2;
            rw2[p3] = v3;
        }
    }
}

// ---------------- pass 3: per-bucket CSR build + deg/dinv (no global atomics) ----------------
__global__ __launch_bounds__(256) void build_kernel(const int* __restrict__ hist,
                                                    const int2* __restrict__ rw2,
                                                    int* __restrict__ off,
                                                    int* __restrict__ cnt,
                                                    float* __restrict__ dinv,
                                                    int2* __restrict__ csr) {
    int b = blockIdx.x;
    int tid = threadIdx.x;
    int begin = hist[b * NB_SORT];
    int end = (b + 1 < NBUCK) ? hist[(b + 1) * NB_SORT] : N_EDGES;
    __shared__ int lcnt[256];
    __shared__ float ldeg[256];
    __shared__ int s[256];
    __shared__ int curo[256];
    lcnt[tid] = 0;
    ldeg[tid] = 0.f;
    __syncthreads();
    for (int e = begin + tid; e < end; e += 512) {
        int2 a = rw2[e];
        int e2 = e + 256;
        int2 c = (e2 < end) ? rw2[e2] : make_int2(0, 0);
        atomicAdd(&lcnt[a.x >> 17], 1);
        atomicAdd(&ldeg[a.x >> 17], __int_as_float(a.y));
        if (e2 < end) {
            atomicAdd(&lcnt[c.x >> 17], 1);
            atomicAdd(&ldeg[c.x >> 17], __int_as_float(c.y));
        }
    }
    __syncthreads();
    int v = lcnt[tid];
    s[tid] = v;
    __syncthreads();
    for (int d = 1; d < 256; d <<= 1) {
        int x = (tid >= d) ? s[tid - d] : 0;
        __syncthreads();
        s[tid] += x;
        __syncthreads();
    }
    int excl = s[tid] - v;
    int node = (b << 8) + tid;
    if (node < N_NODES) {
        off[node] = begin + excl;
        cnt[node] = v;
        dinv[node] = rsqrtf(1.0f + ldeg[tid]);
    }
    curo[tid] = begin + excl;
    __syncthreads();
    for (int e = begin + tid; e < end; e += 512) {
        int2 a = rw2[e];
        int e2 = e + 256;
        int2 c = (e2 < end) ? rw2[e2] : make_int2(0, 0);
        int pa = atomicAdd(&curo[a.x >> 17], 1);
        csr[pa] = make_int2(a.x & ROW_MASK, a.y);
        if (e2 < end) {
            int pc = atomicAdd(&curo[c.x >> 17], 1);
            csr[pc] = make_int2(c.x & ROW_MASK, c.y);
        }
    }
}

// ------- tiled f32 GEMM, bf16 output: H[r,:] = bf16( (X@W)[r,:] * scale[r] ) -------
template <int IN, int OUT, int ROWS>
__global__ __launch_bounds__(256) void gemm_bf16_kernel(const float* __restrict__ X,
                                                        const float* __restrict__ W,
                                                        const float* __restrict__ scale,
                                                        unsigned short* __restrict__ H, int n) {
    constexpr int BK = 16;
    constexpr int TX = OUT / 4;
    constexpr int TY = ROWS / 4;
    static_assert(TX * TY == 256, "block must be 256 threads");
    constexpr int XSS = ROWS + 4;
    constexpr int WSS = OUT + 4;
    __shared__ float xsT[BK][XSS];
    __shared__ float ws[BK][WSS];
    int tid = threadIdx.x;
    int tx = tid % TX, ty = tid / TX;
    int r0 = blockIdx.x * ROWS;
    float acc[4][4] = {};
    for (int k0 = 0; k0 < IN; k0 += BK) {
        constexpr int XL = (ROWS * BK) / (256 * 4);
        #pragma unroll
        for (int l = 0; l < XL; ++l) {
            int t = tid + l * 256;
            int rr = t >> 2;
            int kp = (t & 3) * 4;
            float4 v = make_float4(0.f, 0.f, 0.f, 0.f);
            int gr = r0 + rr;
            if (gr < n) v = *(const float4*)&X[(size_t)gr * IN + k0 + kp];
            xsT[kp + 0][rr] = v.x;
            xsT[kp + 1][rr] = v.y;
            xsT[kp + 2][rr] = v.z;
            xsT[kp + 3][rr] = v.w;
        }
        constexpr int WL = (BK * OUT) / 4;
        if (tid < WL) {
            int kr = tid / TX;
            int cp = (tid % TX) * 4;
            float4 v = *(const float4*)&W[(size_t)(k0 + kr) * OUT + cp];
            *(float4*)&ws[kr][cp] = v;
        }
        __syncthreads();
        #pragma unroll
        for (int kk = 0; kk < BK; ++kk) {
            float4 a = *(const float4*)&xsT[kk][ty * 4];
            float4 b = *(const float4*)&ws[kk][tx * 4];
            float av[4] = {a.x, a.y, a.z, a.w};
            float bv[4] = {b.x, b.y, b.z, b.w};
            #pragma unroll
            for (int i = 0; i < 4; ++i) {
                #pragma unroll
                for (int j = 0; j < 4; ++j) acc[i][j] = fmaf(av[i], bv[j], acc[i][j]);
            }
        }
        __syncthreads();
    }
    #pragma unroll
    for (int i = 0; i < 4; ++i) {
        int gr = r0 + ty * 4 + i;
        if (gr < n) {
            float sc = scale[gr];
            ushort4 o;
            o.x = f2bf(acc[i][0] * sc);
            o.y = f2bf(acc[i][1] * sc);
            o.z = f2bf(acc[i][2] * sc);
            o.w = f2bf(acc[i][3] * sc);
            *(ushort4*)&H[(size_t)gr * OUT + tx * 4] = o;
        }
    }
}

// ---------------- aggregation conv1: 64 feats, wave per node, bf16 gather ----------------
// agg = dinv[n]*(sum_e ew*h~[row] + h~[n]) + b ;  h~ = bf16((X@W)*dinv)
__global__ __launch_bounds__(256) void agg1_kernel(const int2* __restrict__ csr,
                                                   const int* __restrict__ off,
                                                   const int* __restrict__ cnt,
                                                   const float* __restrict__ dinv,
                                                   const unsigned short* __restrict__ h1t,
                                                   const float* __restrict__ b1,
                                                   float* __restrict__ h1p) {
    int lane = threadIdx.x & 63;
    int node = blockIdx.x * 4 + (threadIdx.x >> 6);
    int s = off[node], c = cnt[node];
    float acc = 0.f;
    for (int j0 = 0; j0 < c; j0 += 64) {
        int m = min(64, c - j0);
        int2 e = make_int2(0, 0);
        if (lane < m) e = csr[s + j0 + lane];
        int jj = 0;
        for (; jj + 8 <= m; jj += 8) {
            int r[8], w[8];
            #pragma unroll
            for (int i = 0; i < 8; ++i) {
                r[i] = __builtin_amdgcn_readlane(e.x, jj + i);
                w[i] = __builtin_amdgcn_readlane(e.y, jj + i);
            }
            unsigned short g[8];
            #pragma unroll
            for (int i = 0; i < 8; ++i) g[i] = h1t[(size_t)r[i] * 64 + lane];
            #pragma unroll
            for (int i = 0; i < 8; ++i) acc = fmaf(__int_as_float(w[i]), bf2f(g[i]), acc);
        }
        for (; jj < m; ++jj) {
            int r = __builtin_amdgcn_readlane(e.x, jj);
            float w = __int_as_float(__builtin_amdgcn_readlane(e.y, jj));
            acc = fmaf(w, bf2f(h1t[(size_t)r * 64 + lane]), acc);
        }
    }
    float di = dinv[node];
    float v = (acc + bf2f(h1t[(size_t)node * 64 + lane])) * di + b1[lane];
    h1p[(size_t)node * 64 + lane] = fmaxf(v, 0.f);
}

// ---------------- aggregation conv2: 32 feats, 2 nodes per wave, bf16 gather ----------------
__global__ __launch_bounds__(256) void agg2_kernel(const int2* __restrict__ csr,
                                                   const int* __restrict__ off,
                                                   const int* __restrict__ cnt,
                                                   const float* __restrict__ dinv,
                                                   const unsigned short* __restrict__ h2t,
                                                   const float* __restrict__ b2,
                                                   float* __restrict__ h2p) {
    int f = threadIdx.x & 31;
    int half = (threadIdx.x >> 5) & 1;
    int wid = threadIdx.x >> 6;
    int node = blockIdx.x * 8 + wid * 2 + half;
    int s = off[node], c = cnt[node];
    int base = half * 32;
    float acc = 0.f;
    for (int j0 = 0; j0 < c; j0 += 32) {
        int m = min(32, c - j0);
        int2 e = make_int2(0, 0);
        if (f < m) e = csr[s + j0 + f];
        int jj = 0;
        for (; jj + 4 <= m; jj += 4) {
            int r[4], w[4];
            #pragma unroll
            for (int i = 0; i < 4; ++i) {
                r[i] = __shfl(e.x, base + jj + i);
                w[i] = __shfl(e.y, base + jj + i);
            }
            unsigned short g[4];
            #pragma unroll
            for (int i = 0; i < 4; ++i) g[i] = h2t[(size_t)r[i] * 32 + f];
            #pragma unroll
            for (int i = 0; i < 4; ++i) acc = fmaf(__int_as_float(w[i]), bf2f(g[i]), acc);
        }
        for (; jj < m; ++jj) {
            int r = __shfl(e.x, base + jj);
            float w = __int_as_float(__shfl(e.y, base + jj));
            acc = fmaf(w, bf2f(h2t[(size_t)r * 32 + f]), acc);
        }
    }
    float di = dinv[node];
    float v = (acc + bf2f(h2t[(size_t)node * 32 + f])) * di + b2[f];
    h2p[(size_t)node * 32 + f] = v;
}

// ---------------- pool: one block per graph (batch is sorted) ----------------
__global__ __launch_bounds__(256) void pool_kernel(const float* __restrict__ h2p,
                                                   const int* __restrict__ batch,
                                                   float* __restrict__ u) {
    int g = blockIdx.x;
    int lo = 0, hi = N_NODES;
    while (lo < hi) { int m = (lo + hi) >> 1; if (batch[m] < g) lo = m + 1; else hi = m; }
    int start = lo;
    hi = N_NODES;
    while (lo < hi) { int m = (lo + hi) >> 1; if (batch[m] < g + 1) lo = m + 1; else hi = m; }
    int end = lo;
    int f = threadIdx.x & 31, grp = threadIdx.x >> 5;
    float acc = 0.f;
    for (int n = start + grp; n < end; n += 8) acc += h2p[(size_t)n * 32 + f];
    __shared__ float red[8][32];
    red[grp][f] = acc;
    __syncthreads();
    if (threadIdx.x < 32) {
        float sum = 0.f;
        #pragma unroll
        for (int k = 0; k < 8; ++k) sum += red[k][threadIdx.x];
        u[g * 32 + threadIdx.x] = sum;
    }
}

// ---------------- MLP head ----------------
__global__ __launch_bounds__(256) void head_kernel(const float* __restrict__ u,
                                                   const float* __restrict__ Wl1,
                                                   const float* __restrict__ bl1,
                                                   const float* __restrict__ Wl2,
                                                   const float* __restrict__ bl2,
                                                   float* __restrict__ out) {
    int g = threadIdx.x;
    float uu[32];
    #pragma unroll
    for (int k = 0; k < 32; ++k) uu[k] = u[g * 32 + k];
    float o = bl2[0];
    #pragma unroll
    for (int j = 0; j < 16; ++j) {
        float h = bl1[j];
        #pragma unroll
        for (int k = 0; k < 32; ++k) h = fmaf(uu[k], Wl1[k * 16 + j], h);
        o = fmaf(fmaxf(h, 0.f), Wl2[j], o);
    }
    out[g] = o;
}

extern "C" void kernel_launch(void* const* d_in, const int* in_sizes, int n_in,
                              void* d_out, int out_size, void* d_ws, size_t ws_size,
                              hipStream_t stream) {
    const float* x     = (const float*)d_in[0];
    const int*   ei    = (const int*)d_in[1];
    const float* ew    = (const float*)d_in[2];
    const int*   batch = (const int*)d_in[3];
    const float* W1    = (const float*)d_in[4];
    const float* b1    = (const float*)d_in[5];
    const float* W2    = (const float*)d_in[6];
    const float* b2    = (const float*)d_in[7];
    const float* Wl1   = (const float*)d_in[8];
    const float* bl1   = (const float*)d_in[9];
    const float* Wl2   = (const float*)d_in[10];
    const float* bl2   = (const float*)d_in[11];
    float* out = (float*)d_out;

    const int* row = ei;
    const int* col = ei + N_EDGES;

    char* p = (char*)d_ws;
    auto alloc = [&](size_t bytes) {
        char* q = p;
        p += (bytes + 255) & ~(size_t)255;
        return q;
    };
    int*   hist   = (int*)alloc((size_t)HIST_N * 4);
    int*   bsum   = (int*)alloc(1024 * 4);
    int2*  rw2    = (int2*)alloc((size_t)N_EDGES * 8);
    int*   off    = (int*)alloc(N_NODES * 4);
    int*   cnt    = (int*)alloc(N_NODES * 4);
    float* dinv   = (float*)alloc(N_NODES * 4);
    int2*  csr    = (int2*)alloc((size_t)N_EDGES * 8);
    unsigned short* h1t = (unsigned short*)rw2;  // alias: rw2 dead after build (12.8 MB < 25.6 MB)
    float* h1p    = (float*)alloc((size_t)N_NODES * 64 * 4);
    unsigned short* h2t = (unsigned short*)alloc((size_t)N_NODES * 32 * 2);
    float* h2p    = (float*)alloc((size_t)N_NODES * 32 * 4);
    float* u      = (float*)alloc(N_GRAPHS * 32 * 4);

    const int nbScan = (HIST_N + 4095) / 4096;

    hist_kernel<<<NB_SORT, 256, 0, stream>>>(col, hist);
    scanA_kernel<<<nbScan, 256, 0, stream>>>(hist, bsum, HIST_N);
    scanB_kernel<<<1, 256, 0, stream>>>(bsum, nbScan);
    scanC_kernel<<<(HIST_N + 255) / 256, 256, 0, stream>>>(hist, bsum, HIST_N);
    scatter_sort_kernel<<<NB_SORT, 256, 0, stream>>>(col, row, ew, hist, rw2);
    build_kernel<<<NBUCK, 256, 0, stream>>>(hist, rw2, off, cnt, dinv, csr);

    gemm_bf16_kernel<128, 64, 64><<<(N_NODES + 63) / 64, 256, 0, stream>>>(x, W1, dinv, h1t, N_NODES);
    agg1_kernel<<<(N_NODES + 3) / 4, 256, 0, stream>>>(csr, off, cnt, dinv, h1t, b1, h1p);
    gemm_bf16_kernel<64, 32, 128><<<(N_NODES + 127) / 128, 256, 0, stream>>>(h1p, W2, dinv, h2t, N_NODES);
    agg2_kernel<<<(N_NODES + 7) / 8, 256, 0, stream>>>(csr, off, cnt, dinv, h2t, b2, h2p);
    pool_kernel<<<N_GRAPHS, 256, 0, stream>>>(h2p, batch, u);
    head_kernel<<<1, 256, 0, stream>>>(u, Wl1, bl1, Wl2, bl2, out);
}

// Round 6
// 257.109 us; speedup vs baseline: 3.6240x; 1.1096x over previous
//
#include <hip/hip_runtime.h>
#include <hip/hip_bf16.h>

#define N_NODES 100000
#define N_EDGES 3200000
#define N_GRAPHS 256

#define NBUCK 391                 // ceil(N_NODES / 256) coarse buckets (col >> 8)
#define SORT_ITEMS 2048           // edges per block in hist/scatter passes
#define NB_SORT ((N_EDGES + SORT_ITEMS - 1) / SORT_ITEMS)   // 1563
#define HIST_N (NBUCK * NB_SORT)  // 611,133
#define ROW_MASK 131071           // 2^17 - 1 (N_NODES < 2^17)

__device__ __forceinline__ float bfl(int d) {  // low bf16 of dword -> f32
    return __uint_as_float(((unsigned)d) << 16);
}
__device__ __forceinline__ float bfh(int d) {  // high bf16 of dword -> f32
    return __uint_as_float(((unsigned)d) & 0xffff0000u);
}
__device__ __forceinline__ unsigned short f2bf(float f) {
    __hip_bfloat16 b = __float2bfloat16(f);
    return *(unsigned short*)&b;
}

// ---------------- pass 1: per-block histogram of coarse bucket ----------------
__global__ __launch_bounds__(256) void hist_kernel(const int* __restrict__ col,
                                                   int* __restrict__ hist) {
    __shared__ int h[NBUCK];
    int tid = threadIdx.x;
    for (int i = tid; i < NBUCK; i += 256) h[i] = 0;
    __syncthreads();
    int base = blockIdx.x * SORT_ITEMS + tid * 4;
    #pragma unroll
    for (int l = 0; l < SORT_ITEMS / 1024; ++l) {
        int e = base + l * 1024;
        if (e < N_EDGES) {
            int4 c4 = *(const int4*)&col[e];
            atomicAdd(&h[c4.x >> 8], 1);
            atomicAdd(&h[c4.y >> 8], 1);
            atomicAdd(&h[c4.z >> 8], 1);
            atomicAdd(&h[c4.w >> 8], 1);
        }
    }
    __syncthreads();
    for (int i = tid; i < NBUCK; i += 256) hist[i * NB_SORT + blockIdx.x] = h[i];
}

// ---------------- scan of hist (in place): 4096/block, 2-level ----------------
__global__ __launch_bounds__(256) void scanA_kernel(int* __restrict__ a,
                                                    int* __restrict__ bsum, int n) {
    __shared__ int s[256];
    int tid = threadIdx.x;
    int base = blockIdx.x * 4096 + tid * 16;
    int v[16];
    int sum = 0;
    #pragma unroll
    for (int i = 0; i < 16; ++i) { v[i] = (base + i < n) ? a[base + i] : 0; sum += v[i]; }
    s[tid] = sum;
    __syncthreads();
    for (int d = 1; d < 256; d <<= 1) {
        int x = (tid >= d) ? s[tid - d] : 0;
        __syncthreads();
        s[tid] += x;
        __syncthreads();
    }
    int run = s[tid] - sum;
    #pragma unroll
    for (int i = 0; i < 16; ++i) {
        if (base + i < n) a[base + i] = run;
        run += v[i];
    }
    if (tid == 255) bsum[blockIdx.x] = s[255];
}

__global__ __launch_bounds__(256) void scanB_kernel(int* bsum, int nb) {
    __shared__ int s[256];
    int tid = threadIdx.x;
    int v = (tid < nb) ? bsum[tid] : 0;
    s[tid] = v;
    __syncthreads();
    for (int d = 1; d < 256; d <<= 1) {
        int x = (tid >= d) ? s[tid - d] : 0;
        __syncthreads();
        s[tid] += x;
        __syncthreads();
    }
    if (tid < nb) bsum[tid] = s[tid] - v;  // exclusive
}

__global__ __launch_bounds__(256) void scanC_kernel(int* a, const int* __restrict__ bsum, int n) {
    int i = blockIdx.x * 256 + threadIdx.x;
    if (i < n) a[i] += bsum[i >> 12];
}

// ---------------- pass 2: scatter edges into coarse-bucket regions ----------------
// rw2 entry: { row | (col&255)<<17 , ew }
__global__ __launch_bounds__(256) void scatter_sort_kernel(const int* __restrict__ col,
                                                           const int* __restrict__ row,
                                                           const float* __restrict__ ew,
                                                           const int* __restrict__ hist,
                                                           int2* __restrict__ rw2) {
    __shared__ int offs[NBUCK];
    int tid = threadIdx.x;
    for (int i = tid; i < NBUCK; i += 256) offs[i] = hist[i * NB_SORT + blockIdx.x];
    __syncthreads();
    int base = blockIdx.x * SORT_ITEMS + tid * 4;
    #pragma unroll
    for (int l = 0; l < SORT_ITEMS / 1024; ++l) {
        int e = base + l * 1024;
        if (e < N_EDGES) {
            int4 c4 = *(const int4*)&col[e];
            int4 r4 = *(const int4*)&row[e];
            float4 w4 = *(const float4*)&ew[e];
            int p0 = atomicAdd(&offs[c4.x >> 8], 1);
            int p1 = atomicAdd(&offs[c4.y >> 8], 1);
            int p2 = atomicAdd(&offs[c4.z >> 8], 1);
            int p3 = atomicAdd(&offs[c4.w >> 8], 1);
            int2 v0; v0.x = r4.x | ((c4.x & 255) << 17); v0.y = __float_as_int(w4.x);
            int2 v1; v1.x = r4.y | ((c4.y & 255) << 17); v1.y = __float_as_int(w4.y);
            int2 v2; v2.x = r4.z | ((c4.z & 255) << 17); v2.y = __float_as_int(w4.z);
            int2 v3; v3.x = r4.w | ((c4.w & 255) << 17); v3.y = __float_as_int(w4.w);
            rw2[p0] = v0;
            rw2[p1] = v1;
            rw2[p2] = v2;
            rw2[p3] = v3;
        }
    }
}

// ---------------- pass 3: per-bucket CSR build + deg/dinv (no global atomics) ----------------
__global__ __launch_bounds__(256) void build_kernel(const int* __restrict__ hist,
                                                    const int2* __restrict__ rw2,
                                                    int* __restrict__ off,
                                                    int* __restrict__ cnt,
                                                    float* __restrict__ dinv,
                                                    int2* __restrict__ csr) {
    int b = blockIdx.x;
    int tid = threadIdx.x;
    int begin = hist[b * NB_SORT];
    int end = (b + 1 < NBUCK) ? hist[(b + 1) * NB_SORT] : N_EDGES;
    __shared__ int lcnt[256];
    __shared__ float ldeg[256];
    __shared__ int s[256];
    __shared__ int curo[256];
    lcnt[tid] = 0;
    ldeg[tid] = 0.f;
    __syncthreads();
    for (int e = begin + tid; e < end; e += 512) {
        int2 a = rw2[e];
        int e2 = e + 256;
        int2 c = (e2 < end) ? rw2[e2] : make_int2(0, 0);
        atomicAdd(&lcnt[a.x >> 17], 1);
        atomicAdd(&ldeg[a.x >> 17], __int_as_float(a.y));
        if (e2 < end) {
            atomicAdd(&lcnt[c.x >> 17], 1);
            atomicAdd(&ldeg[c.x >> 17], __int_as_float(c.y));
        }
    }
    __syncthreads();
    int v = lcnt[tid];
    s[tid] = v;
    __syncthreads();
    for (int d = 1; d < 256; d <<= 1) {
        int x = (tid >= d) ? s[tid - d] : 0;
        __syncthreads();
        s[tid] += x;
        __syncthreads();
    }
    int excl = s[tid] - v;
    int node = (b << 8) + tid;
    if (node < N_NODES) {
        off[node] = begin + excl;
        cnt[node] = v;
        dinv[node] = rsqrtf(1.0f + ldeg[tid]);
    }
    curo[tid] = begin + excl;
    __syncthreads();
    for (int e = begin + tid; e < end; e += 512) {
        int2 a = rw2[e];
        int e2 = e + 256;
        int2 c = (e2 < end) ? rw2[e2] : make_int2(0, 0);
        int pa = atomicAdd(&curo[a.x >> 17], 1);
        csr[pa] = make_int2(a.x & ROW_MASK, a.y);
        if (e2 < end) {
            int pc = atomicAdd(&curo[c.x >> 17], 1);
            csr[pc] = make_int2(c.x & ROW_MASK, c.y);
        }
    }
}

// ------- tiled f32 GEMM, bf16 output: H[r,:] = bf16( (X@W)[r,:] * scale[r] ) -------
template <int IN, int OUT, int ROWS>
__global__ __launch_bounds__(256) void gemm_bf16_kernel(const float* __restrict__ X,
                                                        const float* __restrict__ W,
                                                        const float* __restrict__ scale,
                                                        unsigned short* __restrict__ H, int n) {
    constexpr int BK = 16;
    constexpr int TX = OUT / 4;
    constexpr int TY = ROWS / 4;
    static_assert(TX * TY == 256, "block must be 256 threads");
    constexpr int XSS = ROWS + 4;
    constexpr int WSS = OUT + 4;
    __shared__ float xsT[BK][XSS];
    __shared__ float ws[BK][WSS];
    int tid = threadIdx.x;
    int tx = tid % TX, ty = tid / TX;
    int r0 = blockIdx.x * ROWS;
    float acc[4][4] = {};
    for (int k0 = 0; k0 < IN; k0 += BK) {
        constexpr int XL = (ROWS * BK) / (256 * 4);
        #pragma unroll
        for (int l = 0; l < XL; ++l) {
            int t = tid + l * 256;
            int rr = t >> 2;
            int kp = (t & 3) * 4;
            float4 v = make_float4(0.f, 0.f, 0.f, 0.f);
            int gr = r0 + rr;
            if (gr < n) v = *(const float4*)&X[(size_t)gr * IN + k0 + kp];
            xsT[kp + 0][rr] = v.x;
            xsT[kp + 1][rr] = v.y;
            xsT[kp + 2][rr] = v.z;
            xsT[kp + 3][rr] = v.w;
        }
        constexpr int WL = (BK * OUT) / 4;
        if (tid < WL) {
            int kr = tid / TX;
            int cp = (tid % TX) * 4;
            float4 v = *(const float4*)&W[(size_t)(k0 + kr) * OUT + cp];
            *(float4*)&ws[kr][cp] = v;
        }
        __syncthreads();
        #pragma unroll
        for (int kk = 0; kk < BK; ++kk) {
            float4 a = *(const float4*)&xsT[kk][ty * 4];
            float4 b = *(const float4*)&ws[kk][tx * 4];
            float av[4] = {a.x, a.y, a.z, a.w};
            float bv[4] = {b.x, b.y, b.z, b.w};
            #pragma unroll
            for (int i = 0; i < 4; ++i) {
                #pragma unroll
                for (int j = 0; j < 4; ++j) acc[i][j] = fmaf(av[i], bv[j], acc[i][j]);
            }
        }
        __syncthreads();
    }
    #pragma unroll
    for (int i = 0; i < 4; ++i) {
        int gr = r0 + ty * 4 + i;
        if (gr < n) {
            float sc = scale[gr];
            ushort4 o;
            o.x = f2bf(acc[i][0] * sc);
            o.y = f2bf(acc[i][1] * sc);
            o.z = f2bf(acc[i][2] * sc);
            o.w = f2bf(acc[i][3] * sc);
            *(ushort4*)&H[(size_t)gr * OUT + tx * 4] = o;
        }
    }
}

// ---------------- aggregation conv1: 64 feats, wave per node ----------------
// Wave = 8 edge-slots x 8 feat-blocks; each lane loads 16 B (8 bf16) of its slot's row.
// One dwordx4 per 8 edges. Cross-slot reduce once per node via shfl_xor.
__global__ __launch_bounds__(256) void agg1_kernel(const int2* __restrict__ csr,
                                                   const int* __restrict__ off,
                                                   const int* __restrict__ cnt,
                                                   const float* __restrict__ dinv,
                                                   const unsigned short* __restrict__ h1t,
                                                   const float* __restrict__ b1,
                                                   float* __restrict__ h1p) {
    int lane = threadIdx.x & 63;
    int node = blockIdx.x * 4 + (threadIdx.x >> 6);
    int es = lane >> 3;   // edge slot 0..7
    int fb = lane & 7;    // feat block 0..7 (8 feats each)
    int s = off[node], c = cnt[node];
    float acc[8] = {};
    for (int j0 = 0; j0 < c; j0 += 64) {
        int m = min(64, c - j0);
        int2 e = make_int2(0, 0);
        if (lane < m) e = csr[s + j0 + lane];   // lanes >= m: r=0, w=0 -> no-op edges
        int ng = (m + 7) >> 3;
        int g = 0;
        for (; g + 2 <= ng; g += 2) {
            int s0 = g * 8 + es;
            int s1 = s0 + 8;
            int r0 = __shfl(e.x, s0);
            float w0 = __int_as_float(__shfl(e.y, s0));
            int r1 = __shfl(e.x, s1);
            float w1 = __int_as_float(__shfl(e.y, s1));
            int4 d0 = *(const int4*)(h1t + (((size_t)r0) << 6) + (fb << 3));
            int4 d1 = *(const int4*)(h1t + (((size_t)r1) << 6) + (fb << 3));
            acc[0] = fmaf(w0, bfl(d0.x), acc[0]);
            acc[1] = fmaf(w0, bfh(d0.x), acc[1]);
            acc[2] = fmaf(w0, bfl(d0.y), acc[2]);
            acc[3] = fmaf(w0, bfh(d0.y), acc[3]);
            acc[4] = fmaf(w0, bfl(d0.z), acc[4]);
            acc[5] = fmaf(w0, bfh(d0.z), acc[5]);
            acc[6] = fmaf(w0, bfl(d0.w), acc[6]);
            acc[7] = fmaf(w0, bfh(d0.w), acc[7]);
            acc[0] = fmaf(w1, bfl(d1.x), acc[0]);
            acc[1] = fmaf(w1, bfh(d1.x), acc[1]);
            acc[2] = fmaf(w1, bfl(d1.y), acc[2]);
            acc[3] = fmaf(w1, bfh(d1.y), acc[3]);
            acc[4] = fmaf(w1, bfl(d1.z), acc[4]);
            acc[5] = fmaf(w1, bfh(d1.z), acc[5]);
            acc[6] = fmaf(w1, bfl(d1.w), acc[6]);
            acc[7] = fmaf(w1, bfh(d1.w), acc[7]);
        }
        if (g < ng) {
            int s0 = g * 8 + es;
            int r0 = __shfl(e.x, s0);
            float w0 = __int_as_float(__shfl(e.y, s0));
            int4 d0 = *(const int4*)(h1t + (((size_t)r0) << 6) + (fb << 3));
            acc[0] = fmaf(w0, bfl(d0.x), acc[0]);
            acc[1] = fmaf(w0, bfh(d0.x), acc[1]);
            acc[2] = fmaf(w0, bfl(d0.y), acc[2]);
            acc[3] = fmaf(w0, bfh(d0.y), acc[3]);
            acc[4] = fmaf(w0, bfl(d0.z), acc[4]);
            acc[5] = fmaf(w0, bfh(d0.z), acc[5]);
            acc[6] = fmaf(w0, bfl(d0.w), acc[6]);
            acc[7] = fmaf(w0, bfh(d0.w), acc[7]);
        }
    }
    #pragma unroll
    for (int mask = 8; mask <= 32; mask <<= 1) {
        #pragma unroll
        for (int k = 0; k < 8; ++k) acc[k] += __shfl_xor(acc[k], mask);
    }
    if (es == 0) {  // lanes 0..7; fb == lane; feats fb*8 .. fb*8+7
        float di = dinv[node];
        int4 ds = *(const int4*)(h1t + (((size_t)node) << 6) + (fb << 3));
        float4 bv0 = *(const float4*)&b1[fb * 8];
        float4 bv1 = *(const float4*)&b1[fb * 8 + 4];
        float4 o0, o1;
        o0.x = fmaxf(fmaf(acc[0] + bfl(ds.x), di, bv0.x), 0.f);
        o0.y = fmaxf(fmaf(acc[1] + bfh(ds.x), di, bv0.y), 0.f);
        o0.z = fmaxf(fmaf(acc[2] + bfl(ds.y), di, bv0.z), 0.f);
        o0.w = fmaxf(fmaf(acc[3] + bfh(ds.y), di, bv0.w), 0.f);
        o1.x = fmaxf(fmaf(acc[4] + bfl(ds.z), di, bv1.x), 0.f);
        o1.y = fmaxf(fmaf(acc[5] + bfh(ds.z), di, bv1.y), 0.f);
        o1.z = fmaxf(fmaf(acc[6] + bfl(ds.w), di, bv1.z), 0.f);
        o1.w = fmaxf(fmaf(acc[7] + bfh(ds.w), di, bv1.w), 0.f);
        float* po = h1p + (size_t)node * 64 + fb * 8;
        *(float4*)po = o0;
        *(float4*)(po + 4) = o1;
    }
}

// ---------------- aggregation conv2: 32 feats, half-wave per node ----------------
// Half = 8 edge-slots x 4 feat-blocks; lane loads 16 B (8 bf16) of its slot's row.
__global__ __launch_bounds__(256) void agg2_kernel(const int2* __restrict__ csr,
                                                   const int* __restrict__ off,
                                                   const int* __restrict__ cnt,
                                                   const float* __restrict__ dinv,
                                                   const unsigned short* __restrict__ h2t,
                                                   const float* __restrict__ b2,
                                                   float* __restrict__ h2p) {
    int lane = threadIdx.x & 63;
    int half = lane >> 5;
    int hl = lane & 31;
    int es = hl >> 2;   // edge slot 0..7
    int fb = hl & 3;    // feat block 0..3 (8 feats each)
    int wid = threadIdx.x >> 6;
    int node = blockIdx.x * 8 + wid * 2 + half;
    int s = off[node], c = cnt[node];
    int lbase = half << 5;
    float acc[8] = {};
    for (int j0 = 0; j0 < c; j0 += 32) {
        int m = min(32, c - j0);
        int2 e = make_int2(0, 0);
        if (hl < m) e = csr[s + j0 + hl];
        int ng = (m + 7) >> 3;
        int g = 0;
        for (; g + 2 <= ng; g += 2) {
            int s0 = lbase + g * 8 + es;
            int s1 = s0 + 8;
            int r0 = __shfl(e.x, s0);
            float w0 = __int_as_float(__shfl(e.y, s0));
            int r1 = __shfl(e.x, s1);
            float w1 = __int_as_float(__shfl(e.y, s1));
            int4 d0 = *(const int4*)(h2t + (((size_t)r0) << 5) + (fb << 3));
            int4 d1 = *(const int4*)(h2t + (((size_t)r1) << 5) + (fb << 3));
            acc[0] = fmaf(w0, bfl(d0.x), acc[0]);
            acc[1] = fmaf(w0, bfh(d0.x), acc[1]);
            acc[2] = fmaf(w0, bfl(d0.y), acc[2]);
            acc[3] = fmaf(w0, bfh(d0.y), acc[3]);
            acc[4] = fmaf(w0, bfl(d0.z), acc[4]);
            acc[5] = fmaf(w0, bfh(d0.z), acc[5]);
            acc[6] = fmaf(w0, bfl(d0.w), acc[6]);
            acc[7] = fmaf(w0, bfh(d0.w), acc[7]);
            acc[0] = fmaf(w1, bfl(d1.x), acc[0]);
            acc[1] = fmaf(w1, bfh(d1.x), acc[1]);
            acc[2] = fmaf(w1, bfl(d1.y), acc[2]);
            acc[3] = fmaf(w1, bfh(d1.y), acc[3]);
            acc[4] = fmaf(w1, bfl(d1.z), acc[4]);
            acc[5] = fmaf(w1, bfh(d1.z), acc[5]);
            acc[6] = fmaf(w1, bfl(d1.w), acc[6]);
            acc[7] = fmaf(w1, bfh(d1.w), acc[7]);
        }
        if (g < ng) {
            int s0 = lbase + g * 8 + es;
            int r0 = __shfl(e.x, s0);
            float w0 = __int_as_float(__shfl(e.y, s0));
            int4 d0 = *(const int4*)(h2t + (((size_t)r0) << 5) + (fb << 3));
            acc[0] = fmaf(w0, bfl(d0.x), acc[0]);
            acc[1] = fmaf(w0, bfh(d0.x), acc[1]);
            acc[2] = fmaf(w0, bfl(d0.y), acc[2]);
            acc[3] = fmaf(w0, bfh(d0.y), acc[3]);
            acc[4] = fmaf(w0, bfl(d0.z), acc[4]);
            acc[5] = fmaf(w0, bfh(d0.z), acc[5]);
            acc[6] = fmaf(w0, bfl(d0.w), acc[6]);
            acc[7] = fmaf(w0, bfh(d0.w), acc[7]);
        }
    }
    #pragma unroll
    for (int mask = 4; mask <= 16; mask <<= 1) {
        #pragma unroll
        for (int k = 0; k < 8; ++k) acc[k] += __shfl_xor(acc[k], mask);
    }
    if (es == 0) {  // hl 0..3; fb == hl; feats fb*8 .. fb*8+7
        float di = dinv[node];
        int4 ds = *(const int4*)(h2t + (((size_t)node) << 5) + (fb << 3));
        float4 bv0 = *(const float4*)&b2[fb * 8];
        float4 bv1 = *(const float4*)&b2[fb * 8 + 4];
        float4 o0, o1;
        o0.x = fmaf(acc[0] + bfl(ds.x), di, bv0.x);
        o0.y = fmaf(acc[1] + bfh(ds.x), di, bv0.y);
        o0.z = fmaf(acc[2] + bfl(ds.y), di, bv0.z);
        o0.w = fmaf(acc[3] + bfh(ds.y), di, bv0.w);
        o1.x = fmaf(acc[4] + bfl(ds.z), di, bv1.x);
        o1.y = fmaf(acc[5] + bfh(ds.z), di, bv1.y);
        o1.z = fmaf(acc[6] + bfl(ds.w), di, bv1.z);
        o1.w = fmaf(acc[7] + bfh(ds.w), di, bv1.w);
        float* po = h2p + (size_t)node * 32 + fb * 8;
        *(float4*)po = o0;
        *(float4*)(po + 4) = o1;
    }
}

// ---------------- pool: one block per graph (batch is sorted) ----------------
__global__ __launch_bounds__(256) void pool_kernel(const float* __restrict__ h2p,
                                                   const int* __restrict__ batch,
                                                   float* __restrict__ u) {
    int g = blockIdx.x;
    int lo = 0, hi = N_NODES;
    while (lo < hi) { int m = (lo + hi) >> 1; if (batch[m] < g) lo = m + 1; else hi = m; }
    int start = lo;
    hi = N_NODES;
    while (lo < hi) { int m = (lo + hi) >> 1; if (batch[m] < g + 1) lo = m + 1; else hi = m; }
    int end = lo;
    int f = threadIdx.x & 31, grp = threadIdx.x >> 5;
    float acc = 0.f;
    for (int n = start + grp; n < end; n += 8) acc += h2p[(size_t)n * 32 + f];
    __shared__ float red[8][32];
    red[grp][f] = acc;
    __syncthreads();
    if (threadIdx.x < 32) {
        float sum = 0.f;
        #pragma unroll
        for (int k = 0; k < 8; ++k) sum += red[k][threadIdx.x];
        u[g * 32 + threadIdx.x] = sum;
    }
}

// ---------------- MLP head ----------------
__global__ __launch_bounds__(256) void head_kernel(const float* __restrict__ u,
                                                   const float* __restrict__ Wl1,
                                                   const float* __restrict__ bl1,
                                                   const float* __restrict__ Wl2,
                                                   const float* __restrict__ bl2,
                                                   float* __restrict__ out) {
    int g = threadIdx.x;
    float uu[32];
    #pragma unroll
    for (int k = 0; k < 32; ++k) uu[k] = u[g * 32 + k];
    float o = bl2[0];
    #pragma unroll
    for (int j = 0; j < 16; ++j) {
        float h = bl1[j];
        #pragma unroll
        for (int k = 0; k < 32; ++k) h = fmaf(uu[k], Wl1[k * 16 + j], h);
        o = fmaf(fmaxf(h, 0.f), Wl2[j], o);
    }
    out[g] = o;
}

extern "C" void kernel_launch(void* const* d_in, const int* in_sizes, int n_in,
                              void* d_out, int out_size, void* d_ws, size_t ws_size,
                              hipStream_t stream) {
    const float* x     = (const float*)d_in[0];
    const int*   ei    = (const int*)d_in[1];
    const float* ew    = (const float*)d_in[2];
    const int*   batch = (const int*)d_in[3];
    const float* W1    = (const float*)d_in[4];
    const float* b1    = (const float*)d_in[5];
    const float* W2    = (const float*)d_in[6];
    const float* b2    = (const float*)d_in[7];
    const float* Wl1   = (const float*)d_in[8];
    const float* bl1   = (const float*)d_in[9];
    const float* Wl2   = (const float*)d_in[10];
    const float* bl2   = (const float*)d_in[11];
    float* out = (float*)d_out;

    const int* row = ei;
    const int* col = ei + N_EDGES;

    char* p = (char*)d_ws;
    auto alloc = [&](size_t bytes) {
        char* q = p;
        p += (bytes + 255) & ~(size_t)255;
        return q;
    };
    int*   hist   = (int*)alloc((size_t)HIST_N * 4);
    int*   bsum   = (int*)alloc(1024 * 4);
    int2*  rw2    = (int2*)alloc((size_t)N_EDGES * 8);
    int*   off    = (int*)alloc(N_NODES * 4);
    int*   cnt    = (int*)alloc(N_NODES * 4);
    float* dinv   = (float*)alloc(N_NODES * 4);
    int2*  csr    = (int2*)alloc((size_t)N_EDGES * 8);
    unsigned short* h1t = (unsigned short*)rw2;  // alias: rw2 dead after build (12.8 MB < 25.6 MB)
    float* h1p    = (float*)alloc((size_t)N_NODES * 64 * 4);
    unsigned short* h2t = (unsigned short*)alloc((size_t)N_NODES * 32 * 2);
    float* h2p    = (float*)alloc((size_t)N_NODES * 32 * 4);
    float* u      = (float*)alloc(N_GRAPHS * 32 * 4);

    const int nbScan = (HIST_N + 4095) / 4096;

    hist_kernel<<<NB_SORT, 256, 0, stream>>>(col, hist);
    scanA_kernel<<<nbScan, 256, 0, stream>>>(hist, bsum, HIST_N);
    scanB_kernel<<<1, 256, 0, stream>>>(bsum, nbScan);
    scanC_kernel<<<(HIST_N + 255) / 256, 256, 0, stream>>>(hist, bsum, HIST_N);
    scatter_sort_kernel<<<NB_SORT, 256, 0, stream>>>(col, row, ew, hist, rw2);
    build_kernel<<<NBUCK, 256, 0, stream>>>(hist, rw2, off, cnt, dinv, csr);

    gemm_bf16_kernel<128, 64, 64><<<(N_NODES + 63) / 64, 256, 0, stream>>>(x, W1, dinv, h1t, N_NODES);
    agg1_kernel<<<N_NODES / 4, 256, 0, stream>>>(csr, off, cnt, dinv, h1t, b1, h1p);
    gemm_bf16_kernel<64, 32, 128><<<(N_NODES + 127) / 128, 256, 0, stream>>>(h1p, W2, dinv, h2t, N_NODES);
    agg2_kernel<<<N_NODES / 8, 256, 0, stream>>>(csr, off, cnt, dinv, h2t, b2, h2p);
    pool_kernel<<<N_GRAPHS, 256, 0, stream>>>(h2p, batch, u);
    head_kernel<<<1, 256, 0, stream>>>(u, Wl1, bl1, Wl2, bl2, out);
}

// Round 7
// 256.095 us; speedup vs baseline: 3.6383x; 1.0040x over previous
//
#include <hip/hip_runtime.h>
#include <hip/hip_bf16.h>

#define N_NODES 100000
#define N_EDGES 3200000
#define N_GRAPHS 256

#define NBUCK 391                 // ceil(N_NODES / 256) coarse buckets (col >> 8)
#define SORT_ITEMS 4096           // edges per block in hist/scatter passes
#define NB_SORT ((N_EDGES + SORT_ITEMS - 1) / SORT_ITEMS)   // 782
#define HIST_N (NBUCK * NB_SORT)  // 305,762
#define ROW_MASK 131071           // 2^17 - 1 (N_NODES < 2^17)

__device__ __forceinline__ float bfl(int d) {  // low bf16 of dword -> f32
    return __uint_as_float(((unsigned)d) << 16);
}
__device__ __forceinline__ float bfh(int d) {  // high bf16 of dword -> f32
    return __uint_as_float(((unsigned)d) & 0xffff0000u);
}
__device__ __forceinline__ unsigned short f2bf(float f) {
    __hip_bfloat16 b = __float2bfloat16(f);
    return *(unsigned short*)&b;
}

// ---------------- pass 1: per-block histogram of coarse bucket ----------------
__global__ __launch_bounds__(256) void hist_kernel(const int* __restrict__ col,
                                                   int* __restrict__ hist) {
    __shared__ int h[NBUCK];
    int tid = threadIdx.x;
    for (int i = tid; i < NBUCK; i += 256) h[i] = 0;
    __syncthreads();
    int base = blockIdx.x * SORT_ITEMS + tid * 4;
    #pragma unroll
    for (int l = 0; l < SORT_ITEMS / 1024; ++l) {
        int e = base + l * 1024;
        if (e < N_EDGES) {
            int4 c4 = *(const int4*)&col[e];
            atomicAdd(&h[c4.x >> 8], 1);
            atomicAdd(&h[c4.y >> 8], 1);
            atomicAdd(&h[c4.z >> 8], 1);
            atomicAdd(&h[c4.w >> 8], 1);
        }
    }
    __syncthreads();
    for (int i = tid; i < NBUCK; i += 256) hist[i * NB_SORT + blockIdx.x] = h[i];
}

// ---------------- scan of hist (in place): 4096/block, 2-level ----------------
__global__ __launch_bounds__(256) void scanA_kernel(int* __restrict__ a,
                                                    int* __restrict__ bsum, int n) {
    __shared__ int s[256];
    int tid = threadIdx.x;
    int base = blockIdx.x * 4096 + tid * 16;
    int v[16];
    int sum = 0;
    #pragma unroll
    for (int i = 0; i < 16; ++i) { v[i] = (base + i < n) ? a[base + i] : 0; sum += v[i]; }
    s[tid] = sum;
    __syncthreads();
    for (int d = 1; d < 256; d <<= 1) {
        int x = (tid >= d) ? s[tid - d] : 0;
        __syncthreads();
        s[tid] += x;
        __syncthreads();
    }
    int run = s[tid] - sum;
    #pragma unroll
    for (int i = 0; i < 16; ++i) {
        if (base + i < n) a[base + i] = run;
        run += v[i];
    }
    if (tid == 255) bsum[blockIdx.x] = s[255];
}

__global__ __launch_bounds__(256) void scanB_kernel(int* bsum, int nb) {
    __shared__ int s[256];
    int tid = threadIdx.x;
    int v = (tid < nb) ? bsum[tid] : 0;
    s[tid] = v;
    __syncthreads();
    for (int d = 1; d < 256; d <<= 1) {
        int x = (tid >= d) ? s[tid - d] : 0;
        __syncthreads();
        s[tid] += x;
        __syncthreads();
    }
    if (tid < nb) bsum[tid] = s[tid] - v;  // exclusive
}

__global__ __launch_bounds__(256) void scanC_kernel(int* a, const int* __restrict__ bsum, int n) {
    int i = blockIdx.x * 256 + threadIdx.x;
    if (i < n) a[i] += bsum[i >> 12];
}

// ---------------- pass 2: scatter edges into coarse-bucket regions ----------------
// rw2 entry: { row | (col&255)<<17 , ew }
__global__ __launch_bounds__(256) void scatter_sort_kernel(const int* __restrict__ col,
                                                           const int* __restrict__ row,
                                                           const float* __restrict__ ew,
                                                           const int* __restrict__ hist,
                                                           int2* __restrict__ rw2) {
    __shared__ int offs[NBUCK];
    int tid = threadIdx.x;
    for (int i = tid; i < NBUCK; i += 256) offs[i] = hist[i * NB_SORT + blockIdx.x];
    __syncthreads();
    int base = blockIdx.x * SORT_ITEMS + tid * 4;
    #pragma unroll
    for (int l = 0; l < SORT_ITEMS / 1024; ++l) {
        int e = base + l * 1024;
        if (e < N_EDGES) {
            int4 c4 = *(const int4*)&col[e];
            int4 r4 = *(const int4*)&row[e];
            float4 w4 = *(const float4*)&ew[e];
            int p0 = atomicAdd(&offs[c4.x >> 8], 1);
            int p1 = atomicAdd(&offs[c4.y >> 8], 1);
            int p2 = atomicAdd(&offs[c4.z >> 8], 1);
            int p3 = atomicAdd(&offs[c4.w >> 8], 1);
            int2 v0; v0.x = r4.x | ((c4.x & 255) << 17); v0.y = __float_as_int(w4.x);
            int2 v1; v1.x = r4.y | ((c4.y & 255) << 17); v1.y = __float_as_int(w4.y);
            int2 v2; v2.x = r4.z | ((c4.z & 255) << 17); v2.y = __float_as_int(w4.z);
            int2 v3; v3.x = r4.w | ((c4.w & 255) << 17); v3.y = __float_as_int(w4.w);
            rw2[p0] = v0;
            rw2[p1] = v1;
            rw2[p2] = v2;
            rw2[p3] = v3;
        }
    }
}

// ---------------- pass 3: per-bucket CSR build + deg/dinv (no global atomics) ----------------
__global__ __launch_bounds__(256) void build_kernel(const int* __restrict__ hist,
                                                    const int2* __restrict__ rw2,
                                                    int* __restrict__ off,
                                                    int* __restrict__ cnt,
                                                    float* __restrict__ dinv,
                                                    int2* __restrict__ csr) {
    int b = blockIdx.x;
    int tid = threadIdx.x;
    int begin = hist[b * NB_SORT];
    int end = (b + 1 < NBUCK) ? hist[(b + 1) * NB_SORT] : N_EDGES;
    __shared__ int lcnt[256];
    __shared__ float ldeg[256];
    __shared__ int s[256];
    __shared__ int curo[256];
    lcnt[tid] = 0;
    ldeg[tid] = 0.f;
    __syncthreads();
    for (int e = begin + tid; e < end; e += 1024) {
        int2 a0 = rw2[e];
        int e1 = e + 256, e2 = e + 512, e3 = e + 768;
        int2 a1 = (e1 < end) ? rw2[e1] : make_int2(0, 0);
        int2 a2 = (e2 < end) ? rw2[e2] : make_int2(0, 0);
        int2 a3 = (e3 < end) ? rw2[e3] : make_int2(0, 0);
        atomicAdd(&lcnt[a0.x >> 17], 1);
        atomicAdd(&ldeg[a0.x >> 17], __int_as_float(a0.y));
        if (e1 < end) { atomicAdd(&lcnt[a1.x >> 17], 1); atomicAdd(&ldeg[a1.x >> 17], __int_as_float(a1.y)); }
        if (e2 < end) { atomicAdd(&lcnt[a2.x >> 17], 1); atomicAdd(&ldeg[a2.x >> 17], __int_as_float(a2.y)); }
        if (e3 < end) { atomicAdd(&lcnt[a3.x >> 17], 1); atomicAdd(&ldeg[a3.x >> 17], __int_as_float(a3.y)); }
    }
    __syncthreads();
    int v = lcnt[tid];
    s[tid] = v;
    __syncthreads();
    for (int d = 1; d < 256; d <<= 1) {
        int x = (tid >= d) ? s[tid - d] : 0;
        __syncthreads();
        s[tid] += x;
        __syncthreads();
    }
    int excl = s[tid] - v;
    int node = (b << 8) + tid;
    if (node < N_NODES) {
        off[node] = begin + excl;
        cnt[node] = v;
        dinv[node] = rsqrtf(1.0f + ldeg[tid]);
    }
    curo[tid] = begin + excl;
    __syncthreads();
    for (int e = begin + tid; e < end; e += 1024) {
        int2 a0 = rw2[e];
        int e1 = e + 256, e2 = e + 512, e3 = e + 768;
        int2 a1 = (e1 < end) ? rw2[e1] : make_int2(0, 0);
        int2 a2 = (e2 < end) ? rw2[e2] : make_int2(0, 0);
        int2 a3 = (e3 < end) ? rw2[e3] : make_int2(0, 0);
        int p0 = atomicAdd(&curo[a0.x >> 17], 1);
        csr[p0] = make_int2(a0.x & ROW_MASK, a0.y);
        if (e1 < end) { int p = atomicAdd(&curo[a1.x >> 17], 1); csr[p] = make_int2(a1.x & ROW_MASK, a1.y); }
        if (e2 < end) { int p = atomicAdd(&curo[a2.x >> 17], 1); csr[p] = make_int2(a2.x & ROW_MASK, a2.y); }
        if (e3 < end) { int p = atomicAdd(&curo[a3.x >> 17], 1); csr[p] = make_int2(a3.x & ROW_MASK, a3.y); }
    }
}

// ------- tiled f32 GEMM, bf16 output: H[r,:] = bf16( (X@W)[r,:] * scale[r] ) -------
// 8x4 micro-tile per thread.
template <int IN, int OUT, int ROWS>
__global__ __launch_bounds__(256) void gemm_bf16_kernel(const float* __restrict__ X,
                                                        const float* __restrict__ W,
                                                        const float* __restrict__ scale,
                                                        unsigned short* __restrict__ H, int n) {
    constexpr int BK = 16;
    constexpr int TX = OUT / 4;   // thread cols
    constexpr int TY = ROWS / 8;  // thread rows
    static_assert(TX * TY == 256, "block must be 256 threads");
    __shared__ float xsT[BK][ROWS + 4];
    __shared__ float ws[BK][OUT + 4];
    int tid = threadIdx.x;
    int tx = tid % TX, ty = tid / TX;
    int r0 = blockIdx.x * ROWS;
    float acc[8][4] = {};
    for (int k0 = 0; k0 < IN; k0 += BK) {
        constexpr int XL = (ROWS * BK) / (256 * 4);
        #pragma unroll
        for (int l = 0; l < XL; ++l) {
            int t = tid + l * 256;
            int rr = t >> 2;
            int kp = (t & 3) * 4;
            float4 v = make_float4(0.f, 0.f, 0.f, 0.f);
            int gr = r0 + rr;
            if (gr < n) v = *(const float4*)&X[(size_t)gr * IN + k0 + kp];
            xsT[kp + 0][rr] = v.x;
            xsT[kp + 1][rr] = v.y;
            xsT[kp + 2][rr] = v.z;
            xsT[kp + 3][rr] = v.w;
        }
        constexpr int WL = (BK * OUT) / 4;
        if (WL == 256 || tid < WL) {
            int kr = tid / TX;
            int cp = (tid % TX) * 4;
            float4 v = *(const float4*)&W[(size_t)(k0 + kr) * OUT + cp];
            *(float4*)&ws[kr][cp] = v;
        }
        __syncthreads();
        #pragma unroll
        for (int kk = 0; kk < BK; ++kk) {
            float4 a0 = *(const float4*)&xsT[kk][ty * 8];
            float4 a1 = *(const float4*)&xsT[kk][ty * 8 + 4];
            float4 b = *(const float4*)&ws[kk][tx * 4];
            float av[8] = {a0.x, a0.y, a0.z, a0.w, a1.x, a1.y, a1.z, a1.w};
            float bv[4] = {b.x, b.y, b.z, b.w};
            #pragma unroll
            for (int i = 0; i < 8; ++i) {
                #pragma unroll
                for (int j = 0; j < 4; ++j) acc[i][j] = fmaf(av[i], bv[j], acc[i][j]);
            }
        }
        __syncthreads();
    }
    #pragma unroll
    for (int i = 0; i < 8; ++i) {
        int gr = r0 + ty * 8 + i;
        if (gr < n) {
            float sc = scale[gr];
            ushort4 o;
            o.x = f2bf(acc[i][0] * sc);
            o.y = f2bf(acc[i][1] * sc);
            o.z = f2bf(acc[i][2] * sc);
            o.w = f2bf(acc[i][3] * sc);
            *(ushort4*)&H[(size_t)gr * OUT + tx * 4] = o;
        }
    }
}

// ---------------- aggregation conv1: 64 feats, wave per node ----------------
// Wave = 8 edge-slots x 8 feat-blocks; each lane loads 16 B (8 bf16) of its slot's row.
__global__ __launch_bounds__(256) void agg1_kernel(const int2* __restrict__ csr,
                                                   const int* __restrict__ off,
                                                   const int* __restrict__ cnt,
                                                   const float* __restrict__ dinv,
                                                   const unsigned short* __restrict__ h1t,
                                                   const float* __restrict__ b1,
                                                   float* __restrict__ h1p) {
    int lane = threadIdx.x & 63;
    int node = blockIdx.x * 4 + (threadIdx.x >> 6);
    int es = lane >> 3;   // edge slot 0..7
    int fb = lane & 7;    // feat block 0..7 (8 feats each)
    int s = off[node], c = cnt[node];
    float acc[8] = {};
    for (int j0 = 0; j0 < c; j0 += 64) {
        int m = min(64, c - j0);
        int2 e = make_int2(0, 0);
        if (lane < m) e = csr[s + j0 + lane];   // lanes >= m: r=0, w=0 -> no-op edges
        int ng = (m + 7) >> 3;
        int g = 0;
        for (; g + 2 <= ng; g += 2) {
            int s0 = g * 8 + es;
            int s1 = s0 + 8;
            int r0 = __shfl(e.x, s0);
            float w0 = __int_as_float(__shfl(e.y, s0));
            int r1 = __shfl(e.x, s1);
            float w1 = __int_as_float(__shfl(e.y, s1));
            int4 d0 = *(const int4*)(h1t + (((size_t)r0) << 6) + (fb << 3));
            int4 d1 = *(const int4*)(h1t + (((size_t)r1) << 6) + (fb << 3));
            acc[0] = fmaf(w0, bfl(d0.x), acc[0]);
            acc[1] = fmaf(w0, bfh(d0.x), acc[1]);
            acc[2] = fmaf(w0, bfl(d0.y), acc[2]);
            acc[3] = fmaf(w0, bfh(d0.y), acc[3]);
            acc[4] = fmaf(w0, bfl(d0.z), acc[4]);
            acc[5] = fmaf(w0, bfh(d0.z), acc[5]);
            acc[6] = fmaf(w0, bfl(d0.w), acc[6]);
            acc[7] = fmaf(w0, bfh(d0.w), acc[7]);
            acc[0] = fmaf(w1, bfl(d1.x), acc[0]);
            acc[1] = fmaf(w1, bfh(d1.x), acc[1]);
            acc[2] = fmaf(w1, bfl(d1.y), acc[2]);
            acc[3] = fmaf(w1, bfh(d1.y), acc[3]);
            acc[4] = fmaf(w1, bfl(d1.z), acc[4]);
            acc[5] = fmaf(w1, bfh(d1.z), acc[5]);
            acc[6] = fmaf(w1, bfl(d1.w), acc[6]);
            acc[7] = fmaf(w1, bfh(d1.w), acc[7]);
        }
        if (g < ng) {
            int s0 = g * 8 + es;
            int r0 = __shfl(e.x, s0);
            float w0 = __int_as_float(__shfl(e.y, s0));
            int4 d0 = *(const int4*)(h1t + (((size_t)r0) << 6) + (fb << 3));
            acc[0] = fmaf(w0, bfl(d0.x), acc[0]);
            acc[1] = fmaf(w0, bfh(d0.x), acc[1]);
            acc[2] = fmaf(w0, bfl(d0.y), acc[2]);
            acc[3] = fmaf(w0, bfh(d0.y), acc[3]);
            acc[4] = fmaf(w0, bfl(d0.z), acc[4]);
            acc[5] = fmaf(w0, bfh(d0.z), acc[5]);
            acc[6] = fmaf(w0, bfl(d0.w), acc[6]);
            acc[7] = fmaf(w0, bfh(d0.w), acc[7]);
        }
    }
    #pragma unroll
    for (int mask = 8; mask <= 32; mask <<= 1) {
        #pragma unroll
        for (int k = 0; k < 8; ++k) acc[k] += __shfl_xor(acc[k], mask);
    }
    if (es == 0) {  // lanes 0..7; fb == lane; feats fb*8 .. fb*8+7
        float di = dinv[node];
        int4 ds = *(const int4*)(h1t + (((size_t)node) << 6) + (fb << 3));
        float4 bv0 = *(const float4*)&b1[fb * 8];
        float4 bv1 = *(const float4*)&b1[fb * 8 + 4];
        float4 o0, o1;
        o0.x = fmaxf(fmaf(acc[0] + bfl(ds.x), di, bv0.x), 0.f);
        o0.y = fmaxf(fmaf(acc[1] + bfh(ds.x), di, bv0.y), 0.f);
        o0.z = fmaxf(fmaf(acc[2] + bfl(ds.y), di, bv0.z), 0.f);
        o0.w = fmaxf(fmaf(acc[3] + bfh(ds.y), di, bv0.w), 0.f);
        o1.x = fmaxf(fmaf(acc[4] + bfl(ds.z), di, bv1.x), 0.f);
        o1.y = fmaxf(fmaf(acc[5] + bfh(ds.z), di, bv1.y), 0.f);
        o1.z = fmaxf(fmaf(acc[6] + bfl(ds.w), di, bv1.z), 0.f);
        o1.w = fmaxf(fmaf(acc[7] + bfh(ds.w), di, bv1.w), 0.f);
        float* po = h1p + (size_t)node * 64 + fb * 8;
        *(float4*)po = o0;
        *(float4*)(po + 4) = o1;
    }
}

// ---------------- aggregation conv2: 32 feats, half-wave per node ----------------
__global__ __launch_bounds__(256) void agg2_kernel(const int2* __restrict__ csr,
                                                   const int* __restrict__ off,
                                                   const int* __restrict__ cnt,
                                                   const float* __restrict__ dinv,
                                                   const unsigned short* __restrict__ h2t,
                                                   const float* __restrict__ b2,
                                                   float* __restrict__ h2p) {
    int lane = threadIdx.x & 63;
    int half = lane >> 5;
    int hl = lane & 31;
    int es = hl >> 2;   // edge slot 0..7
    int fb = hl & 3;    // feat block 0..3 (8 feats each)
    int wid = threadIdx.x >> 6;
    int node = blockIdx.x * 8 + wid * 2 + half;
    int s = off[node], c = cnt[node];
    int lbase = half << 5;
    float acc[8] = {};
    for (int j0 = 0; j0 < c; j0 += 32) {
        int m = min(32, c - j0);
        int2 e = make_int2(0, 0);
        if (hl < m) e = csr[s + j0 + hl];
        int ng = (m + 7) >> 3;
        int g = 0;
        for (; g + 2 <= ng; g += 2) {
            int s0 = lbase + g * 8 + es;
            int s1 = s0 + 8;
            int r0 = __shfl(e.x, s0);
            float w0 = __int_as_float(__shfl(e.y, s0));
            int r1 = __shfl(e.x, s1);
            float w1 = __int_as_float(__shfl(e.y, s1));
            int4 d0 = *(const int4*)(h2t + (((size_t)r0) << 5) + (fb << 3));
            int4 d1 = *(const int4*)(h2t + (((size_t)r1) << 5) + (fb << 3));
            acc[0] = fmaf(w0, bfl(d0.x), acc[0]);
            acc[1] = fmaf(w0, bfh(d0.x), acc[1]);
            acc[2] = fmaf(w0, bfl(d0.y), acc[2]);
            acc[3] = fmaf(w0, bfh(d0.y), acc[3]);
            acc[4] = fmaf(w0, bfl(d0.z), acc[4]);
            acc[5] = fmaf(w0, bfh(d0.z), acc[5]);
            acc[6] = fmaf(w0, bfl(d0.w), acc[6]);
            acc[7] = fmaf(w0, bfh(d0.w), acc[7]);
            acc[0] = fmaf(w1, bfl(d1.x), acc[0]);
            acc[1] = fmaf(w1, bfh(d1.x), acc[1]);
            acc[2] = fmaf(w1, bfl(d1.y), acc[2]);
            acc[3] = fmaf(w1, bfh(d1.y), acc[3]);
            acc[4] = fmaf(w1, bfl(d1.z), acc[4]);
            acc[5] = fmaf(w1, bfh(d1.z), acc[5]);
            acc[6] = fmaf(w1, bfl(d1.w), acc[6]);
            acc[7] = fmaf(w1, bfh(d1.w), acc[7]);
        }
        if (g < ng) {
            int s0 = lbase + g * 8 + es;
            int r0 = __shfl(e.x, s0);
            float w0 = __int_as_float(__shfl(e.y, s0));
            int4 d0 = *(const int4*)(h2t + (((size_t)r0) << 5) + (fb << 3));
            acc[0] = fmaf(w0, bfl(d0.x), acc[0]);
            acc[1] = fmaf(w0, bfh(d0.x), acc[1]);
            acc[2] = fmaf(w0, bfl(d0.y), acc[2]);
            acc[3] = fmaf(w0, bfh(d0.y), acc[3]);
            acc[4] = fmaf(w0, bfl(d0.z), acc[4]);
            acc[5] = fmaf(w0, bfh(d0.z), acc[5]);
            acc[6] = fmaf(w0, bfl(d0.w), acc[6]);
            acc[7] = fmaf(w0, bfh(d0.w), acc[7]);
        }
    }
    #pragma unroll
    for (int mask = 4; mask <= 16; mask <<= 1) {
        #pragma unroll
        for (int k = 0; k < 8; ++k) acc[k] += __shfl_xor(acc[k], mask);
    }
    if (es == 0) {  // hl 0..3; fb == hl; feats fb*8 .. fb*8+7
        float di = dinv[node];
        int4 ds = *(const int4*)(h2t + (((size_t)node) << 5) + (fb << 3));
        float4 bv0 = *(const float4*)&b2[fb * 8];
        float4 bv1 = *(const float4*)&b2[fb * 8 + 4];
        float4 o0, o1;
        o0.x = fmaf(acc[0] + bfl(ds.x), di, bv0.x);
        o0.y = fmaf(acc[1] + bfh(ds.x), di, bv0.y);
        o0.z = fmaf(acc[2] + bfl(ds.y), di, bv0.z);
        o0.w = fmaf(acc[3] + bfh(ds.y), di, bv0.w);
        o1.x = fmaf(acc[4] + bfl(ds.z), di, bv1.x);
        o1.y = fmaf(acc[5] + bfh(ds.z), di, bv1.y);
        o1.z = fmaf(acc[6] + bfl(ds.w), di, bv1.z);
        o1.w = fmaf(acc[7] + bfh(ds.w), di, bv1.w);
        float* po = h2p + (size_t)node * 32 + fb * 8;
        *(float4*)po = o0;
        *(float4*)(po + 4) = o1;
    }
}

// ---------------- pool: one block per graph (batch is sorted) ----------------
__global__ __launch_bounds__(256) void pool_kernel(const float* __restrict__ h2p,
                                                   const int* __restrict__ batch,
                                                   float* __restrict__ u) {
    int g = blockIdx.x;
    int lo = 0, hi = N_NODES;
    while (lo < hi) { int m = (lo + hi) >> 1; if (batch[m] < g) lo = m + 1; else hi = m; }
    int start = lo;
    hi = N_NODES;
    while (lo < hi) { int m = (lo + hi) >> 1; if (batch[m] < g + 1) lo = m + 1; else hi = m; }
    int end = lo;
    int f = threadIdx.x & 31, grp = threadIdx.x >> 5;
    float acc = 0.f;
    for (int n = start + grp; n < end; n += 8) acc += h2p[(size_t)n * 32 + f];
    __shared__ float red[8][32];
    red[grp][f] = acc;
    __syncthreads();
    if (threadIdx.x < 32) {
        float sum = 0.f;
        #pragma unroll
        for (int k = 0; k < 8; ++k) sum += red[k][threadIdx.x];
        u[g * 32 + threadIdx.x] = sum;
    }
}

// ---------------- MLP head ----------------
__global__ __launch_bounds__(256) void head_kernel(const float* __restrict__ u,
                                                   const float* __restrict__ Wl1,
                                                   const float* __restrict__ bl1,
                                                   const float* __restrict__ Wl2,
                                                   const float* __restrict__ bl2,
                                                   float* __restrict__ out) {
    int g = threadIdx.x;
    float uu[32];
    #pragma unroll
    for (int k = 0; k < 32; ++k) uu[k] = u[g * 32 + k];
    float o = bl2[0];
    #pragma unroll
    for (int j = 0; j < 16; ++j) {
        float h = bl1[j];
        #pragma unroll
        for (int k = 0; k < 32; ++k) h = fmaf(uu[k], Wl1[k * 16 + j], h);
        o = fmaf(fmaxf(h, 0.f), Wl2[j], o);
    }
    out[g] = o;
}

extern "C" void kernel_launch(void* const* d_in, const int* in_sizes, int n_in,
                              void* d_out, int out_size, void* d_ws, size_t ws_size,
                              hipStream_t stream) {
    const float* x     = (const float*)d_in[0];
    const int*   ei    = (const int*)d_in[1];
    const float* ew    = (const float*)d_in[2];
    const int*   batch = (const int*)d_in[3];
    const float* W1    = (const float*)d_in[4];
    const float* b1    = (const float*)d_in[5];
    const float* W2    = (const float*)d_in[6];
    const float* b2    = (const float*)d_in[7];
    const float* Wl1   = (const float*)d_in[8];
    const float* bl1   = (const float*)d_in[9];
    const float* Wl2   = (const float*)d_in[10];
    const float* bl2   = (const float*)d_in[11];
    float* out = (float*)d_out;

    const int* row = ei;
    const int* col = ei + N_EDGES;

    char* p = (char*)d_ws;
    auto alloc = [&](size_t bytes) {
        char* q = p;
        p += (bytes + 255) & ~(size_t)255;
        return q;
    };
    int*   hist   = (int*)alloc((size_t)HIST_N * 4);
    int*   bsum   = (int*)alloc(1024 * 4);
    int2*  rw2    = (int2*)alloc((size_t)N_EDGES * 8);
    int*   off    = (int*)alloc(N_NODES * 4);
    int*   cnt    = (int*)alloc(N_NODES * 4);
    float* dinv   = (float*)alloc(N_NODES * 4);
    int2*  csr    = (int2*)alloc((size_t)N_EDGES * 8);
    unsigned short* h1t = (unsigned short*)rw2;  // alias: rw2 dead after build (12.8 MB < 25.6 MB)
    float* h1p    = (float*)alloc((size_t)N_NODES * 64 * 4);
    unsigned short* h2t = (unsigned short*)alloc((size_t)N_NODES * 32 * 2);
    float* h2p    = (float*)alloc((size_t)N_NODES * 32 * 4);
    float* u      = (float*)alloc(N_GRAPHS * 32 * 4);

    const int nbScan = (HIST_N + 4095) / 4096;

    hist_kernel<<<NB_SORT, 256, 0, stream>>>(col, hist);
    scanA_kernel<<<nbScan, 256, 0, stream>>>(hist, bsum, HIST_N);
    scanB_kernel<<<1, 256, 0, stream>>>(bsum, nbScan);
    scanC_kernel<<<(HIST_N + 255) / 256, 256, 0, stream>>>(hist, bsum, HIST_N);
    scatter_sort_kernel<<<NB_SORT, 256, 0, stream>>>(col, row, ew, hist, rw2);
    build_kernel<<<NBUCK, 256, 0, stream>>>(hist, rw2, off, cnt, dinv, csr);

    gemm_bf16_kernel<128, 64, 128><<<(N_NODES + 127) / 128, 256, 0, stream>>>(x, W1, dinv, h1t, N_NODES);
    agg1_kernel<<<N_NODES / 4, 256, 0, stream>>>(csr, off, cnt, dinv, h1t, b1, h1p);
    gemm_bf16_kernel<64, 32, 256><<<(N_NODES + 255) / 256, 256, 0, stream>>>(h1p, W2, dinv, h2t, N_NODES);
    agg2_kernel<<<N_NODES / 8, 256, 0, stream>>>(csr, off, cnt, dinv, h2t, b2, h2p);
    pool_kernel<<<N_GRAPHS, 256, 0, stream>>>(h2p, batch, u);
    head_kernel<<<1, 256, 0, stream>>>(u, Wl1, bl1, Wl2, bl2, out);
}